// Round 1
// 929.152 us; speedup vs baseline: 1.3692x; 1.3692x over previous
//
#include <hip/hip_runtime.h>
#include <math.h>

#define BB 16
#define CC 256
#define HH 64
#define WW 64
#define HWs 4096
#define PP 65536   // BB*HWs
#define QQ 8
#define NN 9

typedef _Float16 half8_t __attribute__((ext_vector_type(8)));
typedef _Float16 half4_t __attribute__((ext_vector_type(4)));
typedef float floatx4 __attribute__((ext_vector_type(4)));

__device__ __forceinline__ float gelu_f(float x) {
    return 0.5f * x * (1.0f + erff(x * 0.70710678118654752f));
}

// ---------------- weight prep ----------------
__global__ void prep_weights_kernel(const float* __restrict__ off0_w, const float* __restrict__ off1_w,
                                    const float* __restrict__ dw0_w, const float* __restrict__ dw1_w,
                                    const float* __restrict__ op1_w,
                                    const float* __restrict__ in_w, const float* __restrict__ cv_w,
                                    const float* __restrict__ op0_w, const float* __restrict__ op2_w,
                                    const float* __restrict__ out0_w, const float* __restrict__ out1_w,
                                    float* __restrict__ dwt0, float* __restrict__ dwt1,
                                    float* __restrict__ op1t,
                                    _Float16* __restrict__ wh_in, _Float16* __restrict__ wh_cv,
                                    _Float16* __restrict__ wh_op0, _Float16* __restrict__ wh_op2,
                                    _Float16* __restrict__ wh_out0, _Float16* __restrict__ wh_out1,
                                    _Float16* __restrict__ whoff0, _Float16* __restrict__ whoff1) {
    int i = blockIdx.x * 256 + threadIdx.x;
    if (i < 9*256) {
        int c = i & 255;
        int tap = i >> 8;
        dwt0[i] = dw0_w[c*9 + tap];
        dwt1[i] = dw1_w[c*9 + tap];
        op1t[i] = op1_w[c*9 + tap];
    }
    if (i < 65536) {            // [256][256] f16 direct casts
        wh_in[i]  = (_Float16)in_w[i];
        wh_cv[i]  = (_Float16)cv_w[i];
        wh_op0[i] = (_Float16)op0_w[i];
        wh_op2[i] = (_Float16)op2_w[i];
    }
    if (i < 32768) {            // out0: [128][256], out1: [256][128]
        wh_out0[i] = (_Float16)out0_w[i];
        wh_out1[i] = (_Float16)out1_w[i];
    }
    if (i < 9*32*256) {         // whoff[tap][k32][ci], zero-padded k>=27
        int ci = i & 255;
        int k32 = (i >> 8) & 31;
        int tap = i >> 13;
        float v0 = 0.f, v1 = 0.f;
        if (k32 < 27) {
            v0 = off0_w[(k32*256 + ci)*9 + tap];
            v1 = off1_w[(k32*256 + ci)*9 + tap];
        }
        whoff0[i] = (_Float16)v0;
        whoff1[i] = (_Float16)v1;
    }
}

// ---------------- token path ----------------
__global__ void token_kernel(const float* __restrict__ inter, const float* __restrict__ intra,
                             const float* __restrict__ proj_w, const float* __restrict__ proj_b,
                             const float* __restrict__ lin_w, const float* __restrict__ lin_b,
                             const float* __restrict__ tok_g, const float* __restrict__ tok_b,
                             float* __restrict__ t_out) {
    int bq = blockIdx.x;
    int b = bq >> 3, q = bq & 7;
    int c = threadIdx.x;
    __shared__ float inter_s[256];
    __shared__ float pt_s[9];
    __shared__ float g_s[256];
    __shared__ float red[256];
    __shared__ float stat[2];
    inter_s[c] = inter[(b*QQ + q)*CC + c];
    __syncthreads();
    for (int n = 0; n < 9; n++) {
        red[c] = inter_s[c] * intra[(b*NN + n)*CC + c];
        __syncthreads();
        for (int s = 128; s > 0; s >>= 1) {
            if (c < s) red[c] += red[c + s];
            __syncthreads();
        }
        if (c == 0) pt_s[n] = red[0];
        __syncthreads();
    }
    float u = proj_b[c];
    for (int k = 0; k < 256; k++) u += inter_s[k] * proj_w[k*CC + c];
    for (int n = 0; n < 9; n++) u += pt_s[n] * proj_w[(256 + n)*CC + c];
    g_s[c] = gelu_f(u);
    __syncthreads();
    float v = lin_b[c];
    for (int k = 0; k < 256; k++) v += g_s[k] * lin_w[k*CC + c];
    red[c] = v;
    __syncthreads();
    for (int s = 128; s > 0; s >>= 1) { if (c < s) red[c] += red[c + s]; __syncthreads(); }
    if (c == 0) stat[0] = red[0] * (1.0f/256.0f);
    __syncthreads();
    float m = stat[0];
    red[c] = (v - m)*(v - m);
    __syncthreads();
    for (int s = 128; s > 0; s >>= 1) { if (c < s) red[c] += red[c + s]; __syncthreads(); }
    if (c == 0) stat[1] = red[0] * (1.0f/256.0f);
    __syncthreads();
    float var = stat[1];
    float r = rsqrtf(var + 1e-5f);
    t_out[(b*QQ + q)*CC + c] = (v - m) * r * tok_g[c] + tok_b[c];
}

// ---------------- img = ie*(1+pe), NCHW -> NHWC transpose ----------------
__global__ void img_pe_kernel(const float* __restrict__ ie, const float* __restrict__ intra,
                              const float* __restrict__ masks, float* __restrict__ img) {
    int b = blockIdx.z;
    int c0 = blockIdx.y * 32;
    int s0 = blockIdx.x * 32;
    __shared__ float tile[32][33];
    __shared__ float intra_s[9][32];
    __shared__ float mask_s[9][32];
    int tx = threadIdx.x, ty = threadIdx.y;
    int t = ty*32 + tx;
    for (int i = t; i < 288; i += 256) {
        int n = i >> 5, j = i & 31;
        intra_s[n][j] = intra[(b*NN + n)*CC + c0 + j];
        mask_s[n][j]  = masks[(b*NN + n)*HWs + s0 + j];
    }
    __syncthreads();
    #pragma unroll
    for (int r = 0; r < 4; r++) {
        int cl = ty + 8*r;
        float val = ie[(b*CC + c0 + cl)*HWs + s0 + tx];
        float pe = 0.f;
        #pragma unroll
        for (int n = 0; n < 9; n++) pe += intra_s[n][cl] * mask_s[n][tx];
        tile[cl][tx] = val * (1.0f + pe);
    }
    __syncthreads();
    #pragma unroll
    for (int r = 0; r < 4; r++) {
        int sl = ty + 8*r;
        img[(b*HWs + s0 + sl)*CC + c0 + tx] = tile[tx][sl];
    }
}

// ---------------- MFMA 1x1 conv (GEMM) ----------------
// INH: input buffer is f16 [p][CI]; else fp32.
// XH: additionally write f16 copy of the (activated) output.
template<int CI, int CO, int ACT, bool RES, bool INH, bool XH>
__global__ void __launch_bounds__(256) conv1x1_mfma(const void* __restrict__ in, const _Float16* __restrict__ Wh,
        const float* __restrict__ bias, const float* __restrict__ res, float* __restrict__ out,
        _Float16* __restrict__ outh) {
    constexpr int KS = CI/32;        // k-steps
    constexpr int NF = CO/64;        // n-frags per wave
    constexpr int LDR = CI + 8;      // halves per LDS row (+16B pad)
    __shared__ __align__(16) _Float16 a_lds[64*LDR];
    int t = threadIdx.x;
    int wid = t >> 6, lane = t & 63;
    int quad = lane >> 4, l16 = lane & 15;
    int p0 = blockIdx.x * 64;
    if (INH) {
        const half8_t* inh = (const half8_t*)in + (size_t)p0*(CI/8);
        for (int i = t; i < 64*(CI/8); i += 256) {
            int r = i/(CI/8), c8 = i%(CI/8);
            *(half8_t*)&a_lds[r*LDR + c8*8] = inh[i];
        }
    } else {
        const float4* inf = (const float4*)in + (size_t)p0*(CI/4);
        for (int i = t; i < 64*(CI/4); i += 256) {
            float4 v = inf[i];
            half4_t hv; hv[0]=(_Float16)v.x; hv[1]=(_Float16)v.y; hv[2]=(_Float16)v.z; hv[3]=(_Float16)v.w;
            int r = i/(CI/4), c4 = i%(CI/4);
            *(half4_t*)&a_lds[r*LDR + c4*4] = hv;
        }
    }
    __syncthreads();
    int n0 = wid*(CO/4);
    floatx4 acc[4][NF];
    #pragma unroll
    for (int mf = 0; mf < 4; mf++)
        #pragma unroll
        for (int nf = 0; nf < NF; nf++)
            #pragma unroll
            for (int r = 0; r < 4; r++) acc[mf][nf][r] = 0.f;
    for (int ks = 0; ks < KS; ks++) {
        int k = ks*32 + quad*8;
        half8_t a[4];
        #pragma unroll
        for (int mf = 0; mf < 4; mf++)
            a[mf] = *(const half8_t*)&a_lds[(mf*16 + l16)*LDR + k];
        half8_t bfr[NF];
        #pragma unroll
        for (int nf = 0; nf < NF; nf++)
            bfr[nf] = *(const half8_t*)&Wh[(size_t)(n0 + nf*16 + l16)*CI + k];
        #pragma unroll
        for (int mf = 0; mf < 4; mf++)
            #pragma unroll
            for (int nf = 0; nf < NF; nf++)
                acc[mf][nf] = __builtin_amdgcn_mfma_f32_16x16x32_f16(a[mf], bfr[nf], acc[mf][nf], 0, 0, 0);
    }
    // epilogue: C/D col=lane&15 (co), row=quad*4+reg (p)
    #pragma unroll
    for (int nf = 0; nf < NF; nf++) {
        int co = n0 + nf*16 + l16;
        float bs = bias[co];
        #pragma unroll
        for (int mf = 0; mf < 4; mf++) {
            #pragma unroll
            for (int r = 0; r < 4; r++) {
                int p = p0 + mf*16 + quad*4 + r;
                float v = acc[mf][nf][r] + bs;
                if (ACT) v = gelu_f(v);
                if (RES) v += res[(size_t)p*CO + co];
                out[(size_t)p*CO + co] = v;
                if (XH) outh[(size_t)p*CO + co] = (_Float16)v;
            }
        }
    }
}

// ---------------- MFMA 3x3 offset conv (f16 input) -> [p][27] ----------------
template<int DIL>
__global__ void __launch_bounds__(256) off_conv_mfma(const _Float16* __restrict__ x, const _Float16* __restrict__ Wh,
        const float* __restrict__ bias, float* __restrict__ off) {
    constexpr int LDR = 264;    // 256 + 16B pad, halves
    __shared__ __align__(16) _Float16 xs[70*LDR];   // w = -3..66 at idx w+3
    // XCD-aware swizzle: grid 1024 -> each XCD (bid%8) covers 2 consecutive batches
    int raw = blockIdx.x;
    int bh = (raw & 7) * 128 + (raw >> 3);
    int b = bh >> 6, h = bh & 63;
    int t = threadIdx.x;
    int wid = t >> 6, lane = t & 63;
    int quad = lane >> 4, l16 = lane & 15;
    // zero the 6 margin rows once
    for (int i = t; i < 6*LDR; i += 256) {
        int r = i/LDR, c = i%LDR;
        int row = (r < 3) ? r : (64 + r);   // 0,1,2, 67,68,69
        xs[row*LDR + c] = (_Float16)0.f;
    }
    floatx4 acc[2];
    #pragma unroll
    for (int nf = 0; nf < 2; nf++)
        #pragma unroll
        for (int r = 0; r < 4; r++) acc[nf][r] = 0.f;
    for (int ki = 0; ki < 3; ki++) {
        int hrow = h + (ki - 1)*DIL;
        __syncthreads();
        if (hrow >= 0 && hrow < 64) {
            const half8_t* row = (const half8_t*)(x + ((size_t)(b*64 + hrow)*64) * 256);
            for (int i = t; i < 2048; i += 256) {
                int r = i >> 5, c8 = i & 31;
                *(half8_t*)&xs[(r + 3)*LDR + c8*8] = row[r*32 + c8];
            }
        } else {
            half8_t z = (half8_t)((_Float16)0.f);
            for (int i = t; i < 2048; i += 256) {
                int r = i >> 5, c8 = i & 31;
                *(half8_t*)&xs[(r + 3)*LDR + c8*8] = z;
            }
        }
        __syncthreads();
        #pragma unroll
        for (int kj = 0; kj < 3; kj++) {
            const _Float16* wt = Wh + (size_t)(ki*3 + kj)*32*256;
            int wrow = wid*16 + l16 + (kj - 1)*DIL + 3;
            #pragma unroll
            for (int cs = 0; cs < 8; cs++) {
                int k = cs*32 + quad*8;
                half8_t a = *(const half8_t*)&xs[wrow*LDR + k];
                half8_t b0 = *(const half8_t*)&wt[(size_t)l16*256 + k];
                half8_t b1 = *(const half8_t*)&wt[(size_t)(16 + l16)*256 + k];
                acc[0] = __builtin_amdgcn_mfma_f32_16x16x32_f16(a, b0, acc[0], 0, 0, 0);
                acc[1] = __builtin_amdgcn_mfma_f32_16x16x32_f16(a, b1, acc[1], 0, 0, 0);
            }
        }
    }
    int pbase = (b*64 + h)*64;
    #pragma unroll
    for (int nf = 0; nf < 2; nf++) {
        int kcol = nf*16 + l16;
        if (kcol < 27) {
            float bs = bias[kcol];
            #pragma unroll
            for (int r = 0; r < 4; r++) {
                int w = wid*16 + quad*4 + r;
                off[(size_t)(pbase + w)*27 + kcol] = acc[nf][r] + bs;
            }
        }
    }
}

// ---------------- modulated deformable depthwise 3x3 (f16 src/out, fp32 math) ----------------
// grid = BB*HH*2 (w-halves), XCD-swizzled; stage A precomputes per-(w,tap) uniform
// bilinear weights (mask-premultiplied, validity-zeroed) + clamped flat indices in LDS.
template<int DIL>
__global__ void __launch_bounds__(256) deform_kernel(const _Float16* __restrict__ src, const float* __restrict__ off,
        const float* __restrict__ dwt, const float* __restrict__ dwb, _Float16* __restrict__ out) {
    int raw = blockIdx.x;                       // 0..2047
    int swz = (raw & 7) * 256 + (raw >> 3);     // XCD k -> 2 consecutive batches
    int whalf = swz & 1;
    int bh = swz >> 1;
    int b = bh >> 6, h = bh & 63;
    int t = threadIdx.x;
    int c4 = t & 63;
    int ps = t >> 6;

    __shared__ float wq[288*4];
    __shared__ int   iq[288*4];

    // stage A: 32 w x 9 taps, computed once per block (was 64x-redundant per lane)
    for (int j = t; j < 288; j += 256) {
        int lw = j / 9;
        int kk = j - lw*9;
        int w = whalf*32 + lw;
        int p = (b*64 + h)*64 + w;
        const float* op = off + (size_t)p*27;
        float ox = op[kk];
        float oy = op[9 + kk];
        float mm = op[18 + kk];
        mm = 1.0f / (1.0f + expf(-mm));
        int ki = kk / 3, kj = kk - ki*3;
        float py = (float)(h - DIL + ki*DIL) + oy;
        float px = (float)(w - DIL + kj*DIL) + ox;
        float y0f = floorf(py), x0f = floorf(px);
        float wy = py - y0f, wx = px - x0f;
        int y0 = (int)y0f, x0 = (int)x0f;
        int y1 = y0 + 1, x1 = x0 + 1;
        float w00 = (1.f - wy)*(1.f - wx)*mm;
        float w01 = (1.f - wy)*wx*mm;
        float w10 = wy*(1.f - wx)*mm;
        float w11 = wy*wx*mm;
        bool yv0 = (y0 >= 0) && (y0 < 64);
        bool yv1 = (y1 >= 0) && (y1 < 64);
        bool xv0 = (x0 >= 0) && (x0 < 64);
        bool xv1 = (x1 >= 0) && (x1 < 64);
        int y0c = min(max(y0, 0), 63), y1c = min(max(y1, 0), 63);
        int x0c = min(max(x0, 0), 63), x1c = min(max(x1, 0), 63);
        int base = b*4096;
        wq[j*4+0] = (yv0 && xv0) ? w00 : 0.f;
        wq[j*4+1] = (yv0 && xv1) ? w01 : 0.f;
        wq[j*4+2] = (yv1 && xv0) ? w10 : 0.f;
        wq[j*4+3] = (yv1 && xv1) ? w11 : 0.f;
        iq[j*4+0] = base + y0c*64 + x0c;
        iq[j*4+1] = base + y0c*64 + x1c;
        iq[j*4+2] = base + y1c*64 + x0c;
        iq[j*4+3] = base + y1c*64 + x1c;
    }
    __syncthreads();

    float4 dwv[9];
    #pragma unroll
    for (int kk = 0; kk < 9; kk++) dwv[kk] = ((const float4*)dwt)[kk*64 + c4];
    float4 bv = ((const float4*)dwb)[c4];
    const half4_t* srcf = (const half4_t*)src;
    for (int i = 0; i < 8; i++) {
        int lw = ps*8 + i;
        int w = whalf*32 + lw;
        int p = (b*64 + h)*64 + w;
        float4 acc = make_float4(0.f,0.f,0.f,0.f);
        #pragma unroll
        for (int kk = 0; kk < 9; kk++) {
            int q = (lw*9 + kk)*4;
            float a0 = wq[q+0], a1 = wq[q+1], a2 = wq[q+2], a3 = wq[q+3];
            int i0 = iq[q+0], i1 = iq[q+1], i2 = iq[q+2], i3 = iq[q+3];
            half4_t v0 = srcf[(size_t)i0*64 + c4];
            half4_t v1 = srcf[(size_t)i1*64 + c4];
            half4_t v2 = srcf[(size_t)i2*64 + c4];
            half4_t v3 = srcf[(size_t)i3*64 + c4];
            float sx = (float)v0[0]*a0 + (float)v1[0]*a1 + (float)v2[0]*a2 + (float)v3[0]*a3;
            float sy = (float)v0[1]*a0 + (float)v1[1]*a1 + (float)v2[1]*a2 + (float)v3[1]*a3;
            float sz = (float)v0[2]*a0 + (float)v1[2]*a1 + (float)v2[2]*a2 + (float)v3[2]*a3;
            float sw = (float)v0[3]*a0 + (float)v1[3]*a1 + (float)v2[3]*a2 + (float)v3[3]*a3;
            acc.x += sx * dwv[kk].x;
            acc.y += sy * dwv[kk].y;
            acc.z += sz * dwv[kk].z;
            acc.w += sw * dwv[kk].w;
        }
        half4_t o4;
        o4[0] = (_Float16)(acc.x + bv.x);
        o4[1] = (_Float16)(acc.y + bv.y);
        o4[2] = (_Float16)(acc.z + bv.z);
        o4[3] = (_Float16)(acc.w + bv.w);
        ((half4_t*)out)[(size_t)p*64 + c4] = o4;
    }
}

// ---------------- xg = x*a + img; LayerNorm over C ----------------
__global__ void __launch_bounds__(256) gate_ln_kernel(const float* __restrict__ x, const float* __restrict__ a,
        const float* __restrict__ img, const float* __restrict__ g, const float* __restrict__ bb,
        float* __restrict__ out) {
    int t = threadIdx.x;
    int lane = t & 63;
    int wv = t >> 6;
    int p = blockIdx.x*4 + wv;
    float4 xv = ((const float4*)x)[p*64 + lane];
    float4 av = ((const float4*)a)[p*64 + lane];
    float4 iv = ((const float4*)img)[p*64 + lane];
    float4 v;
    v.x = xv.x*av.x + iv.x; v.y = xv.y*av.y + iv.y;
    v.z = xv.z*av.z + iv.z; v.w = xv.w*av.w + iv.w;
    float s = v.x + v.y + v.z + v.w;
    float s2 = v.x*v.x + v.y*v.y + v.z*v.z + v.w*v.w;
    #pragma unroll
    for (int o = 1; o < 64; o <<= 1) { s += __shfl_xor(s, o); s2 += __shfl_xor(s2, o); }
    float m = s * (1.f/256.f);
    float var = s2 * (1.f/256.f) - m*m;
    float r = rsqrtf(var + 1e-5f);
    float4 gv = ((const float4*)g)[lane];
    float4 bv = ((const float4*)bb)[lane];
    float4 o4;
    o4.x = (v.x - m)*r*gv.x + bv.x;
    o4.y = (v.y - m)*r*gv.y + bv.y;
    o4.z = (v.z - m)*r*gv.z + bv.z;
    o4.w = (v.w - m)*r*gv.w + bv.w;
    ((float4*)out)[p*64 + lane] = o4;
}

// ---------------- depthwise 3x3 pad=1 + gelu (NHWC) ----------------
__global__ void __launch_bounds__(256) dw3x3_kernel(const float* __restrict__ in, const float* __restrict__ wt,
        const float* __restrict__ bias, float* __restrict__ out) {
    // XCD-aware swizzle: grid 16384 -> each XCD covers 2 consecutive batches
    int raw = blockIdx.x;
    int swz = (raw & 7) * 2048 + (raw >> 3);
    int gid = swz*256 + threadIdx.x;
    int c4 = gid & 63;
    int p = gid >> 6;
    int w = p & 63;
    int h = (p >> 6) & 63;
    int b = p >> 12;
    float4 acc = ((const float4*)bias)[c4];
    #pragma unroll
    for (int ki = 0; ki < 3; ki++) {
        int hh = h + ki - 1;
        if (hh < 0 || hh >= 64) continue;
        #pragma unroll
        for (int kj = 0; kj < 3; kj++) {
            int wwp = w + kj - 1;
            if (wwp < 0 || wwp >= 64) continue;
            float4 v = ((const float4*)in)[((b*64 + hh)*64 + wwp)*64 + c4];
            float4 wv = ((const float4*)wt)[(ki*3 + kj)*64 + c4];
            acc.x += v.x*wv.x; acc.y += v.y*wv.y; acc.z += v.z*wv.z; acc.w += v.w*wv.w;
        }
    }
    acc.x = gelu_f(acc.x); acc.y = gelu_f(acc.y); acc.z = gelu_f(acc.z); acc.w = gelu_f(acc.w);
    ((float4*)out)[p*64 + c4] = acc;
}

// ---------------- 8-token cross attention + alpha residual ----------------
__global__ void __launch_bounds__(256) attn_kernel(const float* __restrict__ dense, const float* __restrict__ tok,
        const float* __restrict__ alpha, float* __restrict__ out) {
    __shared__ float4 t_s[8*64];
    __shared__ float4 al_s[64];
    int bh = blockIdx.x;
    int b = bh >> 6, h = bh & 63;
    int t = threadIdx.x;
    for (int i = t; i < 512; i += 256) t_s[i] = ((const float4*)tok)[b*512 + i];
    if (t < 64) al_s[t] = ((const float4*)alpha)[t];
    __syncthreads();
    int lane = t & 63, ps = t >> 6;
    for (int i = 0; i < 16; i++) {
        int w = ps*16 + i;
        int p = (b*64 + h)*64 + w;
        float4 dv = ((const float4*)dense)[p*64 + lane];
        float sc[8];
        #pragma unroll
        for (int q = 0; q < 8; q++) {
            float4 tv = t_s[q*64 + lane];
            float partial = dv.x*tv.x + dv.y*tv.y + dv.z*tv.z + dv.w*tv.w;
            #pragma unroll
            for (int o = 1; o < 64; o <<= 1) partial += __shfl_xor(partial, o);
            sc[q] = partial * 0.0625f;   // scale = 256^-0.5
        }
        float mx = sc[0];
        #pragma unroll
        for (int q = 1; q < 8; q++) mx = fmaxf(mx, sc[q]);
        float e[8]; float denom = 0.f;
        #pragma unroll
        for (int q = 0; q < 8; q++) { e[q] = expf(sc[q] - mx); denom += e[q]; }
        float inv = 1.0f / denom;
        float4 al = al_s[lane];
        float4 o4;
        o4.x = dv.x*al.x; o4.y = dv.y*al.y; o4.z = dv.z*al.z; o4.w = dv.w*al.w;
        #pragma unroll
        for (int q = 0; q < 8; q++) {
            float wq = e[q]*inv;
            float4 tv = t_s[q*64 + lane];
            o4.x += wq*tv.x; o4.y += wq*tv.y; o4.z += wq*tv.z; o4.w += wq*tv.w;
        }
        ((float4*)out)[p*64 + lane] = o4;
    }
}

// ---------------- NHWC -> NCHW ----------------
__global__ void nhwc_to_nchw_kernel(const float* __restrict__ in, float* __restrict__ out) {
    int b = blockIdx.z;
    int c0 = blockIdx.y*32, s0 = blockIdx.x*32;
    __shared__ float tile[32][33];
    int tx = threadIdx.x, ty = threadIdx.y;
    #pragma unroll
    for (int r = 0; r < 4; r++) {
        int sl = ty + 8*r;
        tile[tx][sl] = in[(b*HWs + s0 + sl)*CC + c0 + tx];
    }
    __syncthreads();
    #pragma unroll
    for (int r = 0; r < 4; r++) {
        int cl = ty + 8*r;
        out[(b*CC + c0 + cl)*HWs + s0 + tx] = tile[cl][tx];
    }
}

extern "C" void kernel_launch(void* const* d_in, const int* in_sizes, int n_in,
                              void* d_out, int out_size, void* d_ws, size_t ws_size,
                              hipStream_t stream) {
    const float* image_embed = (const float*)d_in[0];
    const float* inter_p     = (const float*)d_in[1];
    const float* intra_p     = (const float*)d_in[2];
    const float* masks       = (const float*)d_in[3];
    const float* proj_w      = (const float*)d_in[4];
    const float* proj_b      = (const float*)d_in[5];
    const float* lin_w       = (const float*)d_in[6];
    const float* lin_b       = (const float*)d_in[7];
    const float* tok_g       = (const float*)d_in[8];
    const float* tok_b       = (const float*)d_in[9];
    const float* alpha       = (const float*)d_in[10];
    const float* in_w        = (const float*)d_in[11];
    const float* in_b        = (const float*)d_in[12];
    const float* off0_w      = (const float*)d_in[13];
    const float* off0_b      = (const float*)d_in[14];
    const float* dw0_w       = (const float*)d_in[15];
    const float* dw0_b       = (const float*)d_in[16];
    const float* off1_w      = (const float*)d_in[17];
    const float* off1_b      = (const float*)d_in[18];
    const float* dw1_w       = (const float*)d_in[19];
    const float* dw1_b       = (const float*)d_in[20];
    const float* cv_w        = (const float*)d_in[21];
    const float* cv_b        = (const float*)d_in[22];
    const float* ln_g        = (const float*)d_in[23];
    const float* ln_b        = (const float*)d_in[24];
    const float* op0_w       = (const float*)d_in[25];
    const float* op0_b       = (const float*)d_in[26];
    const float* op1_w       = (const float*)d_in[27];
    const float* op1_b       = (const float*)d_in[28];
    const float* op2_w       = (const float*)d_in[29];
    const float* op2_b       = (const float*)d_in[30];
    const float* out0_w      = (const float*)d_in[31];
    const float* out0_b      = (const float*)d_in[32];
    const float* out1_w      = (const float*)d_in[33];
    const float* out1_b      = (const float*)d_in[34];
    (void)ws_size; (void)in_sizes; (void)n_in; (void)out_size;

    float* ws = (float*)d_ws;
    const size_t BIG = (size_t)PP * CC;     // 16,777,216 floats (64 MiB)
    float* A   = ws;                        // img -> xln -> o(NHWC)
    float* Bb  = A + BIG;                   // x (fp32) -> y0 -> attn
    float* Cb  = Bb + BIG;                  // [alias: a1h f16 in first half] -> a -> y1 -> o0
    float* D   = (float*)d_out;             // [alias: xh/a2h f16 in first half] -> dense -> final out
    float* OFF = Cb + BIG;                  // [P][27]
    float* TOK = OFF + (size_t)PP*27;       // [16][8][256]
    float* DWT0 = TOK + BB*QQ*CC;
    float* DWT1 = DWT0 + 9*256;
    float* OP1T = DWT1 + 9*256;
    _Float16* WH_IN   = (_Float16*)(OP1T + 9*256);
    _Float16* WH_CV   = WH_IN + 65536;
    _Float16* WH_OP0  = WH_CV + 65536;
    _Float16* WH_OP2  = WH_OP0 + 65536;
    _Float16* WH_OUT0 = WH_OP2 + 65536;
    _Float16* WH_OUT1 = WH_OUT0 + 32768;
    _Float16* WHOFF0  = WH_OUT1 + 32768;
    _Float16* WHOFF1  = WHOFF0 + 9*32*256;
    // f16 aliases (each 32 MiB): XH in d_out (dead before dense written),
    // A1H in Cb (dead before cv output written), A2H reuses XH region.
    _Float16* XH  = (_Float16*)d_out;
    _Float16* A1H = (_Float16*)Cb;
    _Float16* A2H = XH;
    // ws total ~= 209.5 MiB

    prep_weights_kernel<<<(9*32*256 + 255)/256, 256, 0, stream>>>(
        off0_w, off1_w, dw0_w, dw1_w, op1_w,
        in_w, cv_w, op0_w, op2_w, out0_w, out1_w,
        DWT0, DWT1, OP1T,
        WH_IN, WH_CV, WH_OP0, WH_OP2, WH_OUT0, WH_OUT1, WHOFF0, WHOFF1);
    token_kernel<<<BB*QQ, 256, 0, stream>>>(inter_p, intra_p, proj_w, proj_b,
                                            lin_w, lin_b, tok_g, tok_b, TOK);
    // img = ie*(1+pe) -> NHWC
    img_pe_kernel<<<dim3(HWs/32, CC/32, BB), dim3(32,8), 0, stream>>>(image_embed, intra_p, masks, A);
    // x = gelu(conv1x1(img)), fp32 + f16 copy
    conv1x1_mfma<256,256,1,false,false,true><<<PP/64, 256, 0, stream>>>(A, WH_IN, in_b, nullptr, Bb, XH);
    // deform block 1 (dil=1), f16 path
    off_conv_mfma<1><<<BB*HH, 256, 0, stream>>>(XH, WHOFF0, off0_b, OFF);
    deform_kernel<1><<<BB*HH*2, 256, 0, stream>>>(XH, OFF, DWT0, dw0_b, A1H);
    // deform block 2 (dil=3)
    off_conv_mfma<3><<<BB*HH, 256, 0, stream>>>(A1H, WHOFF1, off1_b, OFF);
    deform_kernel<3><<<BB*HH*2, 256, 0, stream>>>(A1H, OFF, DWT1, dw1_b, A2H);
    // a = conv1x1(a2) (f16 in, fp32 out into Cb — a1h alias dead now)
    conv1x1_mfma<256,256,0,false,true,false><<<PP/64, 256, 0, stream>>>(A2H, WH_CV, cv_b, nullptr, Cb, nullptr);
    // x = LN2d(x*a + img)
    gate_ln_kernel<<<PP/4, 256, 0, stream>>>(Bb, Cb, A, ln_g, ln_b, A);
    // y = conv1x1(x)
    conv1x1_mfma<256,256,0,false,false,false><<<PP/64, 256, 0, stream>>>(A, WH_OP0, op0_b, nullptr, Bb, nullptr);
    // y = gelu(dw3x3(y))
    dw3x3_kernel<<<PP*64/256, 256, 0, stream>>>(Bb, OP1T, op1_b, Cb);
    // dense = conv1x1(y) + x  (into d_out; xh/a2h alias dead now)
    conv1x1_mfma<256,256,0,true,false,false><<<PP/64, 256, 0, stream>>>(Cb, WH_OP2, op2_b, A, D, nullptr);
    // attn = softmax-xattn(dense, t) + dense*alpha
    attn_kernel<<<BB*HH, 256, 0, stream>>>(D, TOK, alpha, Bb);
    // o = gelu(conv1x1_128(attn))
    conv1x1_mfma<256,128,1,false,false,false><<<PP/64, 256, 0, stream>>>(Bb, WH_OUT0, out0_b, nullptr, Cb, nullptr);
    // o = conv1x1(o) -> NHWC into A
    conv1x1_mfma<128,256,0,false,false,false><<<PP/64, 256, 0, stream>>>(Cb, WH_OUT1, out1_b, nullptr, A, nullptr);
    // NHWC -> NCHW final output
    nhwc_to_nchw_kernel<<<dim3(HWs/32, CC/32, BB), dim3(32,8), 0, stream>>>(A, (float*)d_out);
}

// Round 2
// 914.042 us; speedup vs baseline: 1.3918x; 1.0165x over previous
//
#include <hip/hip_runtime.h>
#include <math.h>

#define BB 16
#define CC 256
#define HH 64
#define WW 64
#define HWs 4096
#define PP 65536   // BB*HWs
#define QQ 8
#define NN 9

typedef _Float16 half8_t __attribute__((ext_vector_type(8)));
typedef _Float16 half4_t __attribute__((ext_vector_type(4)));
typedef float floatx4 __attribute__((ext_vector_type(4)));

__device__ __forceinline__ float gelu_f(float x) {
    return 0.5f * x * (1.0f + erff(x * 0.70710678118654752f));
}

// ---------------- weight prep ----------------
__global__ void prep_weights_kernel(const float* __restrict__ off0_w, const float* __restrict__ off1_w,
                                    const float* __restrict__ dw0_w, const float* __restrict__ dw1_w,
                                    const float* __restrict__ op1_w,
                                    const float* __restrict__ in_w, const float* __restrict__ cv_w,
                                    const float* __restrict__ op0_w, const float* __restrict__ op2_w,
                                    const float* __restrict__ out0_w, const float* __restrict__ out1_w,
                                    float* __restrict__ dwt0, float* __restrict__ dwt1,
                                    float* __restrict__ op1t,
                                    _Float16* __restrict__ wh_in, _Float16* __restrict__ wh_cv,
                                    _Float16* __restrict__ wh_op0, _Float16* __restrict__ wh_op2,
                                    _Float16* __restrict__ wh_out0, _Float16* __restrict__ wh_out1,
                                    _Float16* __restrict__ whoff0, _Float16* __restrict__ whoff1) {
    int i = blockIdx.x * 256 + threadIdx.x;
    if (i < 9*256) {
        int c = i & 255;
        int tap = i >> 8;
        dwt0[i] = dw0_w[c*9 + tap];
        dwt1[i] = dw1_w[c*9 + tap];
        op1t[i] = op1_w[c*9 + tap];
    }
    if (i < 65536) {            // [256][256] f16 direct casts
        wh_in[i]  = (_Float16)in_w[i];
        wh_cv[i]  = (_Float16)cv_w[i];
        wh_op0[i] = (_Float16)op0_w[i];
        wh_op2[i] = (_Float16)op2_w[i];
    }
    if (i < 32768) {            // out0: [128][256], out1: [256][128]
        wh_out0[i] = (_Float16)out0_w[i];
        wh_out1[i] = (_Float16)out1_w[i];
    }
    if (i < 9*32*256) {         // whoff[tap][k32][ci], zero-padded k>=27
        int ci = i & 255;
        int k32 = (i >> 8) & 31;
        int tap = i >> 13;
        float v0 = 0.f, v1 = 0.f;
        if (k32 < 27) {
            v0 = off0_w[(k32*256 + ci)*9 + tap];
            v1 = off1_w[(k32*256 + ci)*9 + tap];
        }
        whoff0[i] = (_Float16)v0;
        whoff1[i] = (_Float16)v1;
    }
}

// ---------------- token path ----------------
__global__ void token_kernel(const float* __restrict__ inter, const float* __restrict__ intra,
                             const float* __restrict__ proj_w, const float* __restrict__ proj_b,
                             const float* __restrict__ lin_w, const float* __restrict__ lin_b,
                             const float* __restrict__ tok_g, const float* __restrict__ tok_b,
                             float* __restrict__ t_out) {
    int bq = blockIdx.x;
    int b = bq >> 3, q = bq & 7;
    int c = threadIdx.x;
    __shared__ float inter_s[256];
    __shared__ float pt_s[9];
    __shared__ float g_s[256];
    __shared__ float red[256];
    __shared__ float stat[2];
    inter_s[c] = inter[(b*QQ + q)*CC + c];
    __syncthreads();
    for (int n = 0; n < 9; n++) {
        red[c] = inter_s[c] * intra[(b*NN + n)*CC + c];
        __syncthreads();
        for (int s = 128; s > 0; s >>= 1) {
            if (c < s) red[c] += red[c + s];
            __syncthreads();
        }
        if (c == 0) pt_s[n] = red[0];
        __syncthreads();
    }
    float u = proj_b[c];
    for (int k = 0; k < 256; k++) u += inter_s[k] * proj_w[k*CC + c];
    for (int n = 0; n < 9; n++) u += pt_s[n] * proj_w[(256 + n)*CC + c];
    g_s[c] = gelu_f(u);
    __syncthreads();
    float v = lin_b[c];
    for (int k = 0; k < 256; k++) v += g_s[k] * lin_w[k*CC + c];
    red[c] = v;
    __syncthreads();
    for (int s = 128; s > 0; s >>= 1) { if (c < s) red[c] += red[c + s]; __syncthreads(); }
    if (c == 0) stat[0] = red[0] * (1.0f/256.0f);
    __syncthreads();
    float m = stat[0];
    red[c] = (v - m)*(v - m);
    __syncthreads();
    for (int s = 128; s > 0; s >>= 1) { if (c < s) red[c] += red[c + s]; __syncthreads(); }
    if (c == 0) stat[1] = red[0] * (1.0f/256.0f);
    __syncthreads();
    float var = stat[1];
    float r = rsqrtf(var + 1e-5f);
    t_out[(b*QQ + q)*CC + c] = (v - m) * r * tok_g[c] + tok_b[c];
}

// ---------------- img = ie*(1+pe), NCHW -> NHWC transpose ----------------
__global__ void img_pe_kernel(const float* __restrict__ ie, const float* __restrict__ intra,
                              const float* __restrict__ masks, float* __restrict__ img) {
    int b = blockIdx.z;
    int c0 = blockIdx.y * 32;
    int s0 = blockIdx.x * 32;
    __shared__ float tile[32][33];
    __shared__ float intra_s[9][32];
    __shared__ float mask_s[9][32];
    int tx = threadIdx.x, ty = threadIdx.y;
    int t = ty*32 + tx;
    for (int i = t; i < 288; i += 256) {
        int n = i >> 5, j = i & 31;
        intra_s[n][j] = intra[(b*NN + n)*CC + c0 + j];
        mask_s[n][j]  = masks[(b*NN + n)*HWs + s0 + j];
    }
    __syncthreads();
    #pragma unroll
    for (int r = 0; r < 4; r++) {
        int cl = ty + 8*r;
        float val = ie[(b*CC + c0 + cl)*HWs + s0 + tx];
        float pe = 0.f;
        #pragma unroll
        for (int n = 0; n < 9; n++) pe += intra_s[n][cl] * mask_s[n][tx];
        tile[cl][tx] = val * (1.0f + pe);
    }
    __syncthreads();
    #pragma unroll
    for (int r = 0; r < 4; r++) {
        int sl = ty + 8*r;
        img[(b*HWs + s0 + sl)*CC + c0 + tx] = tile[tx][sl];
    }
}

// ---------------- MFMA 1x1 conv (GEMM) ----------------
// INH: input buffer is f16 [p][CI]; else fp32.
// RES: 0 none, 1 fp32 residual, 2 f16 residual
// OUT: 0 fp32 only, 1 f16 only, 2 both
template<int CI, int CO, int ACT, int RES, bool INH, int OUT>
__global__ void __launch_bounds__(256) conv1x1_mfma(const void* __restrict__ in, const _Float16* __restrict__ Wh,
        const float* __restrict__ bias, const void* __restrict__ res, float* __restrict__ out,
        _Float16* __restrict__ outh) {
    constexpr int KS = CI/32;        // k-steps
    constexpr int NF = CO/64;        // n-frags per wave
    constexpr int LDR = CI + 8;      // halves per LDS row (+16B pad)
    __shared__ __align__(16) _Float16 a_lds[64*LDR];
    int t = threadIdx.x;
    int wid = t >> 6, lane = t & 63;
    int quad = lane >> 4, l16 = lane & 15;
    int p0 = blockIdx.x * 64;
    if (INH) {
        const half8_t* inh = (const half8_t*)in + (size_t)p0*(CI/8);
        for (int i = t; i < 64*(CI/8); i += 256) {
            int r = i/(CI/8), c8 = i%(CI/8);
            *(half8_t*)&a_lds[r*LDR + c8*8] = inh[i];
        }
    } else {
        const float4* inf = (const float4*)in + (size_t)p0*(CI/4);
        for (int i = t; i < 64*(CI/4); i += 256) {
            float4 v = inf[i];
            half4_t hv; hv[0]=(_Float16)v.x; hv[1]=(_Float16)v.y; hv[2]=(_Float16)v.z; hv[3]=(_Float16)v.w;
            int r = i/(CI/4), c4 = i%(CI/4);
            *(half4_t*)&a_lds[r*LDR + c4*4] = hv;
        }
    }
    __syncthreads();
    int n0 = wid*(CO/4);
    floatx4 acc[4][NF];
    #pragma unroll
    for (int mf = 0; mf < 4; mf++)
        #pragma unroll
        for (int nf = 0; nf < NF; nf++)
            #pragma unroll
            for (int r = 0; r < 4; r++) acc[mf][nf][r] = 0.f;
    for (int ks = 0; ks < KS; ks++) {
        int k = ks*32 + quad*8;
        half8_t a[4];
        #pragma unroll
        for (int mf = 0; mf < 4; mf++)
            a[mf] = *(const half8_t*)&a_lds[(mf*16 + l16)*LDR + k];
        half8_t bfr[NF];
        #pragma unroll
        for (int nf = 0; nf < NF; nf++)
            bfr[nf] = *(const half8_t*)&Wh[(size_t)(n0 + nf*16 + l16)*CI + k];
        #pragma unroll
        for (int mf = 0; mf < 4; mf++)
            #pragma unroll
            for (int nf = 0; nf < NF; nf++)
                acc[mf][nf] = __builtin_amdgcn_mfma_f32_16x16x32_f16(a[mf], bfr[nf], acc[mf][nf], 0, 0, 0);
    }
    // epilogue: C/D col=lane&15 (co), row=quad*4+reg (p)
    #pragma unroll
    for (int nf = 0; nf < NF; nf++) {
        int co = n0 + nf*16 + l16;
        float bs = bias[co];
        #pragma unroll
        for (int mf = 0; mf < 4; mf++) {
            #pragma unroll
            for (int r = 0; r < 4; r++) {
                int p = p0 + mf*16 + quad*4 + r;
                float v = acc[mf][nf][r] + bs;
                if (ACT) v = gelu_f(v);
                if (RES == 1) v += ((const float*)res)[(size_t)p*CO + co];
                if (RES == 2) v += (float)((const _Float16*)res)[(size_t)p*CO + co];
                if (OUT == 0 || OUT == 2) out[(size_t)p*CO + co] = v;
                if (OUT == 1 || OUT == 2) outh[(size_t)p*CO + co] = (_Float16)v;
            }
        }
    }
}

// ---------------- MFMA 3x3 offset conv (f16 input) -> [p][27] ----------------
template<int DIL>
__global__ void __launch_bounds__(256) off_conv_mfma(const _Float16* __restrict__ x, const _Float16* __restrict__ Wh,
        const float* __restrict__ bias, float* __restrict__ off) {
    constexpr int LDR = 264;    // 256 + 16B pad, halves
    __shared__ __align__(16) _Float16 xs[70*LDR];   // w = -3..66 at idx w+3
    // XCD-aware swizzle: grid 1024 -> each XCD (bid%8) covers 2 consecutive batches
    int raw = blockIdx.x;
    int bh = (raw & 7) * 128 + (raw >> 3);
    int b = bh >> 6, h = bh & 63;
    int t = threadIdx.x;
    int wid = t >> 6, lane = t & 63;
    int quad = lane >> 4, l16 = lane & 15;
    // zero the 6 margin rows once
    for (int i = t; i < 6*LDR; i += 256) {
        int r = i/LDR, c = i%LDR;
        int row = (r < 3) ? r : (64 + r);   // 0,1,2, 67,68,69
        xs[row*LDR + c] = (_Float16)0.f;
    }
    floatx4 acc[2];
    #pragma unroll
    for (int nf = 0; nf < 2; nf++)
        #pragma unroll
        for (int r = 0; r < 4; r++) acc[nf][r] = 0.f;
    for (int ki = 0; ki < 3; ki++) {
        int hrow = h + (ki - 1)*DIL;
        __syncthreads();
        if (hrow >= 0 && hrow < 64) {
            const half8_t* row = (const half8_t*)(x + ((size_t)(b*64 + hrow)*64) * 256);
            for (int i = t; i < 2048; i += 256) {
                int r = i >> 5, c8 = i & 31;
                *(half8_t*)&xs[(r + 3)*LDR + c8*8] = row[r*32 + c8];
            }
        } else {
            half8_t z = (half8_t)((_Float16)0.f);
            for (int i = t; i < 2048; i += 256) {
                int r = i >> 5, c8 = i & 31;
                *(half8_t*)&xs[(r + 3)*LDR + c8*8] = z;
            }
        }
        __syncthreads();
        #pragma unroll
        for (int kj = 0; kj < 3; kj++) {
            const _Float16* wt = Wh + (size_t)(ki*3 + kj)*32*256;
            int wrow = wid*16 + l16 + (kj - 1)*DIL + 3;
            #pragma unroll
            for (int cs = 0; cs < 8; cs++) {
                int k = cs*32 + quad*8;
                half8_t a = *(const half8_t*)&xs[wrow*LDR + k];
                half8_t b0 = *(const half8_t*)&wt[(size_t)l16*256 + k];
                half8_t b1 = *(const half8_t*)&wt[(size_t)(16 + l16)*256 + k];
                acc[0] = __builtin_amdgcn_mfma_f32_16x16x32_f16(a, b0, acc[0], 0, 0, 0);
                acc[1] = __builtin_amdgcn_mfma_f32_16x16x32_f16(a, b1, acc[1], 0, 0, 0);
            }
        }
    }
    int pbase = (b*64 + h)*64;
    #pragma unroll
    for (int nf = 0; nf < 2; nf++) {
        int kcol = nf*16 + l16;
        if (kcol < 27) {
            float bs = bias[kcol];
            #pragma unroll
            for (int r = 0; r < 4; r++) {
                int w = wid*16 + quad*4 + r;
                off[(size_t)(pbase + w)*27 + kcol] = acc[nf][r] + bs;
            }
        }
    }
}

// ---------------- modulated deformable depthwise 3x3 (f16 src/out, fp32 math) ----------------
// grid = BB*HH*2 (w-halves), XCD-swizzled; stage A precomputes per-(w,tap) uniform
// bilinear weights (mask-premultiplied, validity-zeroed) + BYTE offsets in LDS.
// Inner loop: offsets are wave-uniform -> readfirstlane to SGPR, loads are
// scalar-base + per-lane constant offset (no per-lane 64-bit addr math).
template<int DIL>
__global__ void __launch_bounds__(256) deform_kernel(const _Float16* __restrict__ src, const float* __restrict__ off,
        const float* __restrict__ dwt, const float* __restrict__ dwb, _Float16* __restrict__ out) {
    int raw = blockIdx.x;                       // 0..2047
    int swz = (raw & 7) * 256 + (raw >> 3);     // XCD k -> 2 consecutive batches
    int whalf = swz & 1;
    int bh = swz >> 1;
    int b = bh >> 6, h = bh & 63;
    int t = threadIdx.x;
    int c4 = t & 63;
    int ps = t >> 6;

    __shared__ float4 wq4[288];
    __shared__ int4   iq4[288];

    // stage A: 32 w x 9 taps, computed once per block
    for (int j = t; j < 288; j += 256) {
        int lw = j / 9;
        int kk = j - lw*9;
        int w = whalf*32 + lw;
        int p = (b*64 + h)*64 + w;
        const float* op = off + (size_t)p*27;
        float ox = op[kk];
        float oy = op[9 + kk];
        float mm = op[18 + kk];
        mm = 1.0f / (1.0f + expf(-mm));
        int ki = kk / 3, kj = kk - ki*3;
        float py = (float)(h - DIL + ki*DIL) + oy;
        float px = (float)(w - DIL + kj*DIL) + ox;
        float y0f = floorf(py), x0f = floorf(px);
        float wy = py - y0f, wx = px - x0f;
        int y0 = (int)y0f, x0 = (int)x0f;
        int y1 = y0 + 1, x1 = x0 + 1;
        float w00 = (1.f - wy)*(1.f - wx)*mm;
        float w01 = (1.f - wy)*wx*mm;
        float w10 = wy*(1.f - wx)*mm;
        float w11 = wy*wx*mm;
        bool yv0 = (y0 >= 0) && (y0 < 64);
        bool yv1 = (y1 >= 0) && (y1 < 64);
        bool xv0 = (x0 >= 0) && (x0 < 64);
        bool xv1 = (x1 >= 0) && (x1 < 64);
        int y0c = min(max(y0, 0), 63), y1c = min(max(y1, 0), 63);
        int x0c = min(max(x0, 0), 63), x1c = min(max(x1, 0), 63);
        int base = b*4096;
        float4 wv;
        wv.x = (yv0 && xv0) ? w00 : 0.f;
        wv.y = (yv0 && xv1) ? w01 : 0.f;
        wv.z = (yv1 && xv0) ? w10 : 0.f;
        wv.w = (yv1 && xv1) ? w11 : 0.f;
        wq4[j] = wv;
        int4 iv;
        iv.x = (base + y0c*64 + x0c) << 9;   // *512 bytes per pixel (64 ch * 2B... 256ch*2B)
        iv.y = (base + y0c*64 + x1c) << 9;
        iv.z = (base + y1c*64 + x0c) << 9;
        iv.w = (base + y1c*64 + x1c) << 9;
        iq4[j] = iv;
    }
    __syncthreads();

    float4 dwv[9];
    #pragma unroll
    for (int kk = 0; kk < 9; kk++) dwv[kk] = ((const float4*)dwt)[kk*64 + c4];
    float4 bv = ((const float4*)dwb)[c4];
    const char* srcb = (const char*)src + (size_t)c4*8;
    for (int i = 0; i < 8; i++) {
        int lw = ps*8 + i;
        int w = whalf*32 + lw;
        int p = (b*64 + h)*64 + w;
        float4 acc = make_float4(0.f,0.f,0.f,0.f);
        #pragma unroll
        for (int kk = 0; kk < 9; kk++) {
            int j = lw*9 + kk;
            float4 wv = wq4[j];
            int4 iv = iq4[j];
            int o0 = __builtin_amdgcn_readfirstlane(iv.x);
            int o1 = __builtin_amdgcn_readfirstlane(iv.y);
            int o2 = __builtin_amdgcn_readfirstlane(iv.z);
            int o3 = __builtin_amdgcn_readfirstlane(iv.w);
            half4_t v0 = *(const half4_t*)(srcb + o0);
            half4_t v1 = *(const half4_t*)(srcb + o1);
            half4_t v2 = *(const half4_t*)(srcb + o2);
            half4_t v3 = *(const half4_t*)(srcb + o3);
            float sx = (float)v0[0]*wv.x + (float)v1[0]*wv.y + (float)v2[0]*wv.z + (float)v3[0]*wv.w;
            float sy = (float)v0[1]*wv.x + (float)v1[1]*wv.y + (float)v2[1]*wv.z + (float)v3[1]*wv.w;
            float sz = (float)v0[2]*wv.x + (float)v1[2]*wv.y + (float)v2[2]*wv.z + (float)v3[2]*wv.w;
            float sw = (float)v0[3]*wv.x + (float)v1[3]*wv.y + (float)v2[3]*wv.z + (float)v3[3]*wv.w;
            acc.x += sx * dwv[kk].x;
            acc.y += sy * dwv[kk].y;
            acc.z += sz * dwv[kk].z;
            acc.w += sw * dwv[kk].w;
        }
        half4_t o4;
        o4[0] = (_Float16)(acc.x + bv.x);
        o4[1] = (_Float16)(acc.y + bv.y);
        o4[2] = (_Float16)(acc.z + bv.z);
        o4[3] = (_Float16)(acc.w + bv.w);
        ((half4_t*)out)[(size_t)p*64 + c4] = o4;
    }
}

// ---------------- xg = x*a + img; LayerNorm over C (f16 x,a; fp32 img; f16 out) ----------------
__global__ void __launch_bounds__(256) gate_ln_kernel(const _Float16* __restrict__ x, const _Float16* __restrict__ a,
        const float* __restrict__ img, const float* __restrict__ g, const float* __restrict__ bb,
        _Float16* __restrict__ out) {
    int t = threadIdx.x;
    int lane = t & 63;
    int wv = t >> 6;
    int p = blockIdx.x*4 + wv;
    half4_t xh = ((const half4_t*)x)[p*64 + lane];
    half4_t ah = ((const half4_t*)a)[p*64 + lane];
    float4 iv = ((const float4*)img)[p*64 + lane];
    float4 v;
    v.x = (float)xh[0]*(float)ah[0] + iv.x;
    v.y = (float)xh[1]*(float)ah[1] + iv.y;
    v.z = (float)xh[2]*(float)ah[2] + iv.z;
    v.w = (float)xh[3]*(float)ah[3] + iv.w;
    float s = v.x + v.y + v.z + v.w;
    float s2 = v.x*v.x + v.y*v.y + v.z*v.z + v.w*v.w;
    #pragma unroll
    for (int o = 1; o < 64; o <<= 1) { s += __shfl_xor(s, o); s2 += __shfl_xor(s2, o); }
    float m = s * (1.f/256.f);
    float var = s2 * (1.f/256.f) - m*m;
    float r = rsqrtf(var + 1e-5f);
    float4 gv = ((const float4*)g)[lane];
    float4 bv = ((const float4*)bb)[lane];
    half4_t o4;
    o4[0] = (_Float16)((v.x - m)*r*gv.x + bv.x);
    o4[1] = (_Float16)((v.y - m)*r*gv.y + bv.y);
    o4[2] = (_Float16)((v.z - m)*r*gv.z + bv.z);
    o4[3] = (_Float16)((v.w - m)*r*gv.w + bv.w);
    ((half4_t*)out)[p*64 + lane] = o4;
}

// ---------------- depthwise 3x3 pad=1 + gelu (NHWC, f16 in/out) ----------------
__global__ void __launch_bounds__(256) dw3x3_kernel(const _Float16* __restrict__ in, const float* __restrict__ wt,
        const float* __restrict__ bias, _Float16* __restrict__ out) {
    // XCD-aware swizzle: grid 16384 -> each XCD covers 2 consecutive batches
    int raw = blockIdx.x;
    int swz = (raw & 7) * 2048 + (raw >> 3);
    int gid = swz*256 + threadIdx.x;
    int c4 = gid & 63;
    int p = gid >> 6;
    int w = p & 63;
    int h = (p >> 6) & 63;
    int b = p >> 12;
    float4 acc = ((const float4*)bias)[c4];
    #pragma unroll
    for (int ki = 0; ki < 3; ki++) {
        int hh = h + ki - 1;
        if (hh < 0 || hh >= 64) continue;
        #pragma unroll
        for (int kj = 0; kj < 3; kj++) {
            int wwp = w + kj - 1;
            if (wwp < 0 || wwp >= 64) continue;
            half4_t v = ((const half4_t*)in)[((b*64 + hh)*64 + wwp)*64 + c4];
            float4 wv = ((const float4*)wt)[(ki*3 + kj)*64 + c4];
            acc.x += (float)v[0]*wv.x; acc.y += (float)v[1]*wv.y;
            acc.z += (float)v[2]*wv.z; acc.w += (float)v[3]*wv.w;
        }
    }
    half4_t o4;
    o4[0] = (_Float16)gelu_f(acc.x);
    o4[1] = (_Float16)gelu_f(acc.y);
    o4[2] = (_Float16)gelu_f(acc.z);
    o4[3] = (_Float16)gelu_f(acc.w);
    ((half4_t*)out)[p*64 + c4] = o4;
}

// ---------------- 8-token cross attention + alpha residual (f16 dense/out) ----------------
__global__ void __launch_bounds__(256) attn_kernel(const _Float16* __restrict__ dense, const float* __restrict__ tok,
        const float* __restrict__ alpha, _Float16* __restrict__ out) {
    __shared__ float4 t_s[8*64];
    __shared__ float4 al_s[64];
    int bh = blockIdx.x;
    int b = bh >> 6, h = bh & 63;
    int t = threadIdx.x;
    for (int i = t; i < 512; i += 256) t_s[i] = ((const float4*)tok)[b*512 + i];
    if (t < 64) al_s[t] = ((const float4*)alpha)[t];
    __syncthreads();
    int lane = t & 63, ps = t >> 6;
    for (int i = 0; i < 16; i++) {
        int w = ps*16 + i;
        int p = (b*64 + h)*64 + w;
        half4_t dh = ((const half4_t*)dense)[(size_t)p*64 + lane];
        float4 dv;
        dv.x = (float)dh[0]; dv.y = (float)dh[1]; dv.z = (float)dh[2]; dv.w = (float)dh[3];
        float sc[8];
        #pragma unroll
        for (int q = 0; q < 8; q++) {
            float4 tv = t_s[q*64 + lane];
            float partial = dv.x*tv.x + dv.y*tv.y + dv.z*tv.z + dv.w*tv.w;
            #pragma unroll
            for (int o = 1; o < 64; o <<= 1) partial += __shfl_xor(partial, o);
            sc[q] = partial * 0.0625f;   // scale = 256^-0.5
        }
        float mx = sc[0];
        #pragma unroll
        for (int q = 1; q < 8; q++) mx = fmaxf(mx, sc[q]);
        float e[8]; float denom = 0.f;
        #pragma unroll
        for (int q = 0; q < 8; q++) { e[q] = expf(sc[q] - mx); denom += e[q]; }
        float inv = 1.0f / denom;
        float4 al = al_s[lane];
        float4 o4;
        o4.x = dv.x*al.x; o4.y = dv.y*al.y; o4.z = dv.z*al.z; o4.w = dv.w*al.w;
        #pragma unroll
        for (int q = 0; q < 8; q++) {
            float wq = e[q]*inv;
            float4 tv = t_s[q*64 + lane];
            o4.x += wq*tv.x; o4.y += wq*tv.y; o4.z += wq*tv.z; o4.w += wq*tv.w;
        }
        half4_t oh;
        oh[0] = (_Float16)o4.x; oh[1] = (_Float16)o4.y;
        oh[2] = (_Float16)o4.z; oh[3] = (_Float16)o4.w;
        ((half4_t*)out)[(size_t)p*64 + lane] = oh;
    }
}

// ---------------- NHWC -> NCHW ----------------
__global__ void nhwc_to_nchw_kernel(const float* __restrict__ in, float* __restrict__ out) {
    int b = blockIdx.z;
    int c0 = blockIdx.y*32, s0 = blockIdx.x*32;
    __shared__ float tile[32][33];
    int tx = threadIdx.x, ty = threadIdx.y;
    #pragma unroll
    for (int r = 0; r < 4; r++) {
        int sl = ty + 8*r;
        tile[tx][sl] = in[(b*HWs + s0 + sl)*CC + c0 + tx];
    }
    __syncthreads();
    #pragma unroll
    for (int r = 0; r < 4; r++) {
        int cl = ty + 8*r;
        out[(b*CC + c0 + cl)*HWs + s0 + tx] = tile[cl][tx];
    }
}

extern "C" void kernel_launch(void* const* d_in, const int* in_sizes, int n_in,
                              void* d_out, int out_size, void* d_ws, size_t ws_size,
                              hipStream_t stream) {
    const float* image_embed = (const float*)d_in[0];
    const float* inter_p     = (const float*)d_in[1];
    const float* intra_p     = (const float*)d_in[2];
    const float* masks       = (const float*)d_in[3];
    const float* proj_w      = (const float*)d_in[4];
    const float* proj_b      = (const float*)d_in[5];
    const float* lin_w       = (const float*)d_in[6];
    const float* lin_b       = (const float*)d_in[7];
    const float* tok_g       = (const float*)d_in[8];
    const float* tok_b       = (const float*)d_in[9];
    const float* alpha       = (const float*)d_in[10];
    const float* in_w        = (const float*)d_in[11];
    const float* in_b        = (const float*)d_in[12];
    const float* off0_w      = (const float*)d_in[13];
    const float* off0_b      = (const float*)d_in[14];
    const float* dw0_w       = (const float*)d_in[15];
    const float* dw0_b       = (const float*)d_in[16];
    const float* off1_w      = (const float*)d_in[17];
    const float* off1_b      = (const float*)d_in[18];
    const float* dw1_w       = (const float*)d_in[19];
    const float* dw1_b       = (const float*)d_in[20];
    const float* cv_w        = (const float*)d_in[21];
    const float* cv_b        = (const float*)d_in[22];
    const float* ln_g        = (const float*)d_in[23];
    const float* ln_b        = (const float*)d_in[24];
    const float* op0_w       = (const float*)d_in[25];
    const float* op0_b       = (const float*)d_in[26];
    const float* op1_w       = (const float*)d_in[27];
    const float* op1_b       = (const float*)d_in[28];
    const float* op2_w       = (const float*)d_in[29];
    const float* op2_b       = (const float*)d_in[30];
    const float* out0_w      = (const float*)d_in[31];
    const float* out0_b      = (const float*)d_in[32];
    const float* out1_w      = (const float*)d_in[33];
    const float* out1_b      = (const float*)d_in[34];
    (void)ws_size; (void)in_sizes; (void)n_in; (void)out_size;

    float* ws = (float*)d_ws;
    const size_t BIG = (size_t)PP * CC;     // 16,777,216 floats (64 MiB)
    float* A   = ws;                        // img fp32 -> (Y0H|Y1H f16) -> o(NHWC fp32)
    float* Bb  = A + BIG;                   // XH|A1H f16 -> ATH f16
    float* Cb  = Bb + BIG;                  // A2H|AH f16 -> DENH|O0H f16
    float* OFF = Cb + BIG;                  // [P][27]
    float* TOK = OFF + (size_t)PP*27;       // [16][8][256]
    float* DWT0 = TOK + BB*QQ*CC;
    float* DWT1 = DWT0 + 9*256;
    float* OP1T = DWT1 + 9*256;
    _Float16* WH_IN   = (_Float16*)(OP1T + 9*256);
    _Float16* WH_CV   = WH_IN + 65536;
    _Float16* WH_OP0  = WH_CV + 65536;
    _Float16* WH_OP2  = WH_OP0 + 65536;
    _Float16* WH_OUT0 = WH_OP2 + 65536;
    _Float16* WH_OUT1 = WH_OUT0 + 32768;
    _Float16* WHOFF0  = WH_OUT1 + 32768;
    _Float16* WHOFF1  = WHOFF0 + 9*32*256;
    // f16 tensor aliases (each 32 MiB = PP*CC halves)
    _Float16* XH   = (_Float16*)Bb;              // x f16
    _Float16* A1H  = XH + (size_t)PP*CC;         // deform1 out
    _Float16* A2H  = (_Float16*)Cb;              // deform2 out
    _Float16* AH   = A2H + (size_t)PP*CC;        // a = cv out
    _Float16* XLNH = (_Float16*)d_out;           // LN out (d_out lower half; dead before final)
    _Float16* Y0H  = (_Float16*)A;               // op0 out (img dead after gate_ln)
    _Float16* Y1H  = Y0H + (size_t)PP*CC;        // dw3x3 out
    _Float16* DENH = (_Float16*)Cb;              // dense (A2H dead)
    _Float16* ATH  = (_Float16*)Bb;              // attn out (XH dead)
    _Float16* O0H  = (_Float16*)Cb + (size_t)PP*CC;  // out0 out, 16 MiB (AH dead)

    prep_weights_kernel<<<(9*32*256 + 255)/256, 256, 0, stream>>>(
        off0_w, off1_w, dw0_w, dw1_w, op1_w,
        in_w, cv_w, op0_w, op2_w, out0_w, out1_w,
        DWT0, DWT1, OP1T,
        WH_IN, WH_CV, WH_OP0, WH_OP2, WH_OUT0, WH_OUT1, WHOFF0, WHOFF1);
    token_kernel<<<BB*QQ, 256, 0, stream>>>(inter_p, intra_p, proj_w, proj_b,
                                            lin_w, lin_b, tok_g, tok_b, TOK);
    // img = ie*(1+pe) -> NHWC fp32
    img_pe_kernel<<<dim3(HWs/32, CC/32, BB), dim3(32,8), 0, stream>>>(image_embed, intra_p, masks, A);
    // x = gelu(conv1x1(img)) -> f16 only
    conv1x1_mfma<256,256,1,0,false,1><<<PP/64, 256, 0, stream>>>(A, WH_IN, in_b, nullptr, nullptr, XH);
    // deform block 1 (dil=1)
    off_conv_mfma<1><<<BB*HH, 256, 0, stream>>>(XH, WHOFF0, off0_b, OFF);
    deform_kernel<1><<<BB*HH*2, 256, 0, stream>>>(XH, OFF, DWT0, dw0_b, A1H);
    // deform block 2 (dil=3)
    off_conv_mfma<3><<<BB*HH, 256, 0, stream>>>(A1H, WHOFF1, off1_b, OFF);
    deform_kernel<3><<<BB*HH*2, 256, 0, stream>>>(A1H, OFF, DWT1, dw1_b, A2H);
    // a = conv1x1(a2) -> f16
    conv1x1_mfma<256,256,0,0,true,1><<<PP/64, 256, 0, stream>>>(A2H, WH_CV, cv_b, nullptr, nullptr, AH);
    // x_ln = LN2d(x*a + img) -> f16
    gate_ln_kernel<<<PP/4, 256, 0, stream>>>(XH, AH, A, ln_g, ln_b, XLNH);
    // y0 = conv1x1(x_ln) -> f16
    conv1x1_mfma<256,256,0,0,true,1><<<PP/64, 256, 0, stream>>>(XLNH, WH_OP0, op0_b, nullptr, nullptr, Y0H);
    // y1 = gelu(dw3x3(y0)) -> f16
    dw3x3_kernel<<<PP*64/256, 256, 0, stream>>>(Y0H, OP1T, op1_b, Y1H);
    // dense = conv1x1(y1) + x_ln -> f16
    conv1x1_mfma<256,256,0,2,true,1><<<PP/64, 256, 0, stream>>>(Y1H, WH_OP2, op2_b, XLNH, nullptr, DENH);
    // attn = softmax-xattn(dense, t) + dense*alpha -> f16
    attn_kernel<<<BB*HH, 256, 0, stream>>>(DENH, TOK, alpha, ATH);
    // o0 = gelu(conv1x1_128(attn)) -> f16
    conv1x1_mfma<256,128,1,0,true,1><<<PP/64, 256, 0, stream>>>(ATH, WH_OUT0, out0_b, nullptr, nullptr, O0H);
    // o = conv1x1(o0) -> NHWC fp32 into A
    conv1x1_mfma<128,256,0,0,true,0><<<PP/64, 256, 0, stream>>>(O0H, WH_OUT1, out1_b, nullptr, A, nullptr);
    // NHWC -> NCHW final output
    nhwc_to_nchw_kernel<<<dim3(HWs/32, CC/32, BB), dim3(32,8), 0, stream>>>(A, (float*)d_out);
}

// Round 3
// 813.450 us; speedup vs baseline: 1.5639x; 1.1237x over previous
//
#include <hip/hip_runtime.h>
#include <math.h>

#define BB 16
#define CC 256
#define HH 64
#define WW 64
#define HWs 4096
#define PP 65536   // BB*HWs
#define QQ 8
#define NN 9

typedef _Float16 half8_t __attribute__((ext_vector_type(8)));
typedef _Float16 half4_t __attribute__((ext_vector_type(4)));
typedef float floatx4 __attribute__((ext_vector_type(4)));

__device__ __forceinline__ float gelu_f(float x) {
    return 0.5f * x * (1.0f + erff(x * 0.70710678118654752f));
}

// ---------------- weight prep ----------------
__global__ void prep_weights_kernel(const float* __restrict__ off0_w, const float* __restrict__ off1_w,
                                    const float* __restrict__ dw0_w, const float* __restrict__ dw1_w,
                                    const float* __restrict__ op1_w,
                                    const float* __restrict__ in_w, const float* __restrict__ cv_w,
                                    const float* __restrict__ op0_w, const float* __restrict__ op2_w,
                                    const float* __restrict__ out0_w, const float* __restrict__ out1_w,
                                    float* __restrict__ dwt0, float* __restrict__ dwt1,
                                    float* __restrict__ op1t,
                                    _Float16* __restrict__ wh_in, _Float16* __restrict__ wh_cv,
                                    _Float16* __restrict__ wh_op0, _Float16* __restrict__ wh_op2,
                                    _Float16* __restrict__ wh_out0, _Float16* __restrict__ wh_out1,
                                    _Float16* __restrict__ whoff0, _Float16* __restrict__ whoff1) {
    int i = blockIdx.x * 256 + threadIdx.x;
    if (i < 9*256) {
        int c = i & 255;
        int tap = i >> 8;
        dwt0[i] = dw0_w[c*9 + tap];
        dwt1[i] = dw1_w[c*9 + tap];
        op1t[i] = op1_w[c*9 + tap];
    }
    if (i < 65536) {            // [256][256] f16 direct casts
        wh_in[i]  = (_Float16)in_w[i];
        wh_cv[i]  = (_Float16)cv_w[i];
        wh_op0[i] = (_Float16)op0_w[i];
        wh_op2[i] = (_Float16)op2_w[i];
    }
    if (i < 32768) {            // out0: [128][256], out1: [256][128]
        wh_out0[i] = (_Float16)out0_w[i];
        wh_out1[i] = (_Float16)out1_w[i];
    }
    if (i < 9*32*256) {         // whoff[tap][k32][ci], zero-padded k>=27
        int ci = i & 255;
        int k32 = (i >> 8) & 31;
        int tap = i >> 13;
        float v0 = 0.f, v1 = 0.f;
        if (k32 < 27) {
            v0 = off0_w[(k32*256 + ci)*9 + tap];
            v1 = off1_w[(k32*256 + ci)*9 + tap];
        }
        whoff0[i] = (_Float16)v0;
        whoff1[i] = (_Float16)v1;
    }
}

// ---------------- token path ----------------
__global__ void token_kernel(const float* __restrict__ inter, const float* __restrict__ intra,
                             const float* __restrict__ proj_w, const float* __restrict__ proj_b,
                             const float* __restrict__ lin_w, const float* __restrict__ lin_b,
                             const float* __restrict__ tok_g, const float* __restrict__ tok_b,
                             float* __restrict__ t_out) {
    int bq = blockIdx.x;
    int b = bq >> 3, q = bq & 7;
    int c = threadIdx.x;
    __shared__ float inter_s[256];
    __shared__ float pt_s[9];
    __shared__ float g_s[256];
    __shared__ float red[256];
    __shared__ float stat[2];
    inter_s[c] = inter[(b*QQ + q)*CC + c];
    __syncthreads();
    for (int n = 0; n < 9; n++) {
        red[c] = inter_s[c] * intra[(b*NN + n)*CC + c];
        __syncthreads();
        for (int s = 128; s > 0; s >>= 1) {
            if (c < s) red[c] += red[c + s];
            __syncthreads();
        }
        if (c == 0) pt_s[n] = red[0];
        __syncthreads();
    }
    float u = proj_b[c];
    for (int k = 0; k < 256; k++) u += inter_s[k] * proj_w[k*CC + c];
    for (int n = 0; n < 9; n++) u += pt_s[n] * proj_w[(256 + n)*CC + c];
    g_s[c] = gelu_f(u);
    __syncthreads();
    float v = lin_b[c];
    for (int k = 0; k < 256; k++) v += g_s[k] * lin_w[k*CC + c];
    red[c] = v;
    __syncthreads();
    for (int s = 128; s > 0; s >>= 1) { if (c < s) red[c] += red[c + s]; __syncthreads(); }
    if (c == 0) stat[0] = red[0] * (1.0f/256.0f);
    __syncthreads();
    float m = stat[0];
    red[c] = (v - m)*(v - m);
    __syncthreads();
    for (int s = 128; s > 0; s >>= 1) { if (c < s) red[c] += red[c + s]; __syncthreads(); }
    if (c == 0) stat[1] = red[0] * (1.0f/256.0f);
    __syncthreads();
    float var = stat[1];
    float r = rsqrtf(var + 1e-5f);
    t_out[(b*QQ + q)*CC + c] = (v - m) * r * tok_g[c] + tok_b[c];
}

// ---------------- img = ie*(1+pe), NCHW -> NHWC transpose ----------------
__global__ void img_pe_kernel(const float* __restrict__ ie, const float* __restrict__ intra,
                              const float* __restrict__ masks, float* __restrict__ img) {
    int b = blockIdx.z;
    int c0 = blockIdx.y * 32;
    int s0 = blockIdx.x * 32;
    __shared__ float tile[32][33];
    __shared__ float intra_s[9][32];
    __shared__ float mask_s[9][32];
    int tx = threadIdx.x, ty = threadIdx.y;
    int t = ty*32 + tx;
    for (int i = t; i < 288; i += 256) {
        int n = i >> 5, j = i & 31;
        intra_s[n][j] = intra[(b*NN + n)*CC + c0 + j];
        mask_s[n][j]  = masks[(b*NN + n)*HWs + s0 + j];
    }
    __syncthreads();
    #pragma unroll
    for (int r = 0; r < 4; r++) {
        int cl = ty + 8*r;
        float val = ie[(b*CC + c0 + cl)*HWs + s0 + tx];
        float pe = 0.f;
        #pragma unroll
        for (int n = 0; n < 9; n++) pe += intra_s[n][cl] * mask_s[n][tx];
        tile[cl][tx] = val * (1.0f + pe);
    }
    __syncthreads();
    #pragma unroll
    for (int r = 0; r < 4; r++) {
        int sl = ty + 8*r;
        img[(b*HWs + s0 + sl)*CC + c0 + tx] = tile[tx][sl];
    }
}

// ---------------- MFMA 1x1 conv (GEMM) ----------------
// INH: input buffer is f16 [p][CI]; else fp32.
// RES: 0 none, 1 fp32 residual, 2 f16 residual
// OUT: 0 fp32 NHWC, 1 f16 only, 2 both, 3 fp32 NCHW direct (fused final transpose)
template<int CI, int CO, int ACT, int RES, bool INH, int OUT>
__global__ void __launch_bounds__(256) conv1x1_mfma(const void* __restrict__ in, const _Float16* __restrict__ Wh,
        const float* __restrict__ bias, const void* __restrict__ res, float* __restrict__ out,
        _Float16* __restrict__ outh) {
    constexpr int KS = CI/32;        // k-steps
    constexpr int NF = CO/64;        // n-frags per wave
    constexpr int LDR = CI + 8;      // halves per LDS row (+16B pad)
    __shared__ __align__(16) _Float16 a_lds[64*LDR];
    int t = threadIdx.x;
    int wid = t >> 6, lane = t & 63;
    int quad = lane >> 4, l16 = lane & 15;
    int p0 = blockIdx.x * 64;
    if (INH) {
        const half8_t* inh = (const half8_t*)in + (size_t)p0*(CI/8);
        for (int i = t; i < 64*(CI/8); i += 256) {
            int r = i/(CI/8), c8 = i%(CI/8);
            *(half8_t*)&a_lds[r*LDR + c8*8] = inh[i];
        }
    } else {
        const float4* inf = (const float4*)in + (size_t)p0*(CI/4);
        for (int i = t; i < 64*(CI/4); i += 256) {
            float4 v = inf[i];
            half4_t hv; hv[0]=(_Float16)v.x; hv[1]=(_Float16)v.y; hv[2]=(_Float16)v.z; hv[3]=(_Float16)v.w;
            int r = i/(CI/4), c4 = i%(CI/4);
            *(half4_t*)&a_lds[r*LDR + c4*4] = hv;
        }
    }
    __syncthreads();
    int n0 = wid*(CO/4);
    floatx4 acc[4][NF];
    #pragma unroll
    for (int mf = 0; mf < 4; mf++)
        #pragma unroll
        for (int nf = 0; nf < NF; nf++)
            #pragma unroll
            for (int r = 0; r < 4; r++) acc[mf][nf][r] = 0.f;
    for (int ks = 0; ks < KS; ks++) {
        int k = ks*32 + quad*8;
        half8_t a[4];
        #pragma unroll
        for (int mf = 0; mf < 4; mf++)
            a[mf] = *(const half8_t*)&a_lds[(mf*16 + l16)*LDR + k];
        half8_t bfr[NF];
        #pragma unroll
        for (int nf = 0; nf < NF; nf++)
            bfr[nf] = *(const half8_t*)&Wh[(size_t)(n0 + nf*16 + l16)*CI + k];
        #pragma unroll
        for (int mf = 0; mf < 4; mf++)
            #pragma unroll
            for (int nf = 0; nf < NF; nf++)
                acc[mf][nf] = __builtin_amdgcn_mfma_f32_16x16x32_f16(a[mf], bfr[nf], acc[mf][nf], 0, 0, 0);
    }
    // epilogue: C/D col=lane&15 (co), row=quad*4+reg (p)
    size_t bb = (size_t)(p0 >> 12) * ((size_t)CO * HWs) + (size_t)(p0 & 4095);
    #pragma unroll
    for (int nf = 0; nf < NF; nf++) {
        int co = n0 + nf*16 + l16;
        float bs = bias[co];
        #pragma unroll
        for (int mf = 0; mf < 4; mf++) {
            #pragma unroll
            for (int r = 0; r < 4; r++) {
                int p = p0 + mf*16 + quad*4 + r;
                float v = acc[mf][nf][r] + bs;
                if (ACT) v = gelu_f(v);
                if (RES == 1) v += ((const float*)res)[(size_t)p*CO + co];
                if (RES == 2) v += (float)((const _Float16*)res)[(size_t)p*CO + co];
                if (OUT == 0 || OUT == 2) out[(size_t)p*CO + co] = v;
                if (OUT == 1 || OUT == 2) outh[(size_t)p*CO + co] = (_Float16)v;
                if (OUT == 3) out[bb + (size_t)co*HWs + (mf*16 + quad*4 + r)] = v;
            }
        }
    }
}

// ---------------- MFMA 3x3 offset conv (f16 input) -> [p][27] ----------------
template<int DIL>
__global__ void __launch_bounds__(256) off_conv_mfma(const _Float16* __restrict__ x, const _Float16* __restrict__ Wh,
        const float* __restrict__ bias, float* __restrict__ off) {
    constexpr int LDR = 264;    // 256 + 16B pad, halves
    __shared__ __align__(16) _Float16 xs[70*LDR];   // w = -3..66 at idx w+3
    // XCD-aware swizzle: grid 1024 -> each XCD (bid%8) covers 2 consecutive batches
    int raw = blockIdx.x;
    int bh = (raw & 7) * 128 + (raw >> 3);
    int b = bh >> 6, h = bh & 63;
    int t = threadIdx.x;
    int wid = t >> 6, lane = t & 63;
    int quad = lane >> 4, l16 = lane & 15;
    // zero the 6 margin rows once
    for (int i = t; i < 6*LDR; i += 256) {
        int r = i/LDR, c = i%LDR;
        int row = (r < 3) ? r : (64 + r);   // 0,1,2, 67,68,69
        xs[row*LDR + c] = (_Float16)0.f;
    }
    floatx4 acc[2];
    #pragma unroll
    for (int nf = 0; nf < 2; nf++)
        #pragma unroll
        for (int r = 0; r < 4; r++) acc[nf][r] = 0.f;
    for (int ki = 0; ki < 3; ki++) {
        int hrow = h + (ki - 1)*DIL;
        __syncthreads();
        if (hrow >= 0 && hrow < 64) {
            const half8_t* row = (const half8_t*)(x + ((size_t)(b*64 + hrow)*64) * 256);
            for (int i = t; i < 2048; i += 256) {
                int r = i >> 5, c8 = i & 31;
                *(half8_t*)&xs[(r + 3)*LDR + c8*8] = row[r*32 + c8];
            }
        } else {
            half8_t z = (half8_t)((_Float16)0.f);
            for (int i = t; i < 2048; i += 256) {
                int r = i >> 5, c8 = i & 31;
                *(half8_t*)&xs[(r + 3)*LDR + c8*8] = z;
            }
        }
        __syncthreads();
        #pragma unroll
        for (int kj = 0; kj < 3; kj++) {
            const _Float16* wt = Wh + (size_t)(ki*3 + kj)*32*256;
            int wrow = wid*16 + l16 + (kj - 1)*DIL + 3;
            #pragma unroll
            for (int cs = 0; cs < 8; cs++) {
                int k = cs*32 + quad*8;
                half8_t a = *(const half8_t*)&xs[wrow*LDR + k];
                half8_t b0 = *(const half8_t*)&wt[(size_t)l16*256 + k];
                half8_t b1 = *(const half8_t*)&wt[(size_t)(16 + l16)*256 + k];
                acc[0] = __builtin_amdgcn_mfma_f32_16x16x32_f16(a, b0, acc[0], 0, 0, 0);
                acc[1] = __builtin_amdgcn_mfma_f32_16x16x32_f16(a, b1, acc[1], 0, 0, 0);
            }
        }
    }
    int pbase = (b*64 + h)*64;
    #pragma unroll
    for (int nf = 0; nf < 2; nf++) {
        int kcol = nf*16 + l16;
        if (kcol < 27) {
            float bs = bias[kcol];
            #pragma unroll
            for (int r = 0; r < 4; r++) {
                int w = wid*16 + quad*4 + r;
                off[(size_t)(pbase + w)*27 + kcol] = acc[nf][r] + bs;
            }
        }
    }
}

// ---------------- modulated deformable depthwise 3x3 (f16 src/out, fp32 math) ----------------
// Stage A: per-(w,tap) uniform bilinear weights + byte offsets in LDS.
// Inner loop: issue all 36 corner loads (scalar-base via readfirstlane) into
// registers FIRST (deep ILP to cover L2 latency), then accumulate.
template<int DIL>
__global__ void __launch_bounds__(256, 3) deform_kernel(const _Float16* __restrict__ src, const float* __restrict__ off,
        const float* __restrict__ dwt, const float* __restrict__ dwb, _Float16* __restrict__ out) {
    int raw = blockIdx.x;                       // 0..2047
    int swz = (raw & 7) * 256 + (raw >> 3);     // XCD k -> 2 consecutive batches
    int whalf = swz & 1;
    int bh = swz >> 1;
    int b = bh >> 6, h = bh & 63;
    int t = threadIdx.x;
    int c4 = t & 63;
    int ps = t >> 6;

    __shared__ float4 wq4[288];
    __shared__ int4   iq4[288];
    __shared__ float  dw_lds[9*256];

    for (int i = t; i < 9*256; i += 256) dw_lds[i] = dwt[i];

    // stage A: 32 w x 9 taps, computed once per block
    for (int j = t; j < 288; j += 256) {
        int lw = j / 9;
        int kk = j - lw*9;
        int w = whalf*32 + lw;
        int p = (b*64 + h)*64 + w;
        const float* op = off + (size_t)p*27;
        float ox = op[kk];
        float oy = op[9 + kk];
        float mm = op[18 + kk];
        mm = 1.0f / (1.0f + expf(-mm));
        int ki = kk / 3, kj = kk - ki*3;
        float py = (float)(h - DIL + ki*DIL) + oy;
        float px = (float)(w - DIL + kj*DIL) + ox;
        float y0f = floorf(py), x0f = floorf(px);
        float wy = py - y0f, wx = px - x0f;
        int y0 = (int)y0f, x0 = (int)x0f;
        int y1 = y0 + 1, x1 = x0 + 1;
        float w00 = (1.f - wy)*(1.f - wx)*mm;
        float w01 = (1.f - wy)*wx*mm;
        float w10 = wy*(1.f - wx)*mm;
        float w11 = wy*wx*mm;
        bool yv0 = (y0 >= 0) && (y0 < 64);
        bool yv1 = (y1 >= 0) && (y1 < 64);
        bool xv0 = (x0 >= 0) && (x0 < 64);
        bool xv1 = (x1 >= 0) && (x1 < 64);
        int y0c = min(max(y0, 0), 63), y1c = min(max(y1, 0), 63);
        int x0c = min(max(x0, 0), 63), x1c = min(max(x1, 0), 63);
        int base = b*4096;
        float4 wv;
        wv.x = (yv0 && xv0) ? w00 : 0.f;
        wv.y = (yv0 && xv1) ? w01 : 0.f;
        wv.z = (yv1 && xv0) ? w10 : 0.f;
        wv.w = (yv1 && xv1) ? w11 : 0.f;
        wq4[j] = wv;
        int4 iv;
        iv.x = (base + y0c*64 + x0c) << 9;   // *512 B per pixel (256 ch * 2B)
        iv.y = (base + y0c*64 + x1c) << 9;
        iv.z = (base + y1c*64 + x0c) << 9;
        iv.w = (base + y1c*64 + x1c) << 9;
        iq4[j] = iv;
    }
    __syncthreads();

    float4 bv = ((const float4*)dwb)[c4];
    const char* srcb = (const char*)src + (size_t)c4*8;
    for (int i = 0; i < 8; i++) {
        int lw = ps*8 + i;
        int jb = lw*9;
        int w = whalf*32 + lw;
        int p = (b*64 + h)*64 + w;
        // phase A: issue all 36 corner loads
        half4_t v[9][4];
        #pragma unroll
        for (int kk = 0; kk < 9; kk++) {
            int4 iv = iq4[jb + kk];
            int o0 = __builtin_amdgcn_readfirstlane(iv.x);
            int o1 = __builtin_amdgcn_readfirstlane(iv.y);
            int o2 = __builtin_amdgcn_readfirstlane(iv.z);
            int o3 = __builtin_amdgcn_readfirstlane(iv.w);
            v[kk][0] = *(const half4_t*)(srcb + o0);
            v[kk][1] = *(const half4_t*)(srcb + o1);
            v[kk][2] = *(const half4_t*)(srcb + o2);
            v[kk][3] = *(const half4_t*)(srcb + o3);
        }
        // phase B: accumulate
        float4 acc = make_float4(0.f,0.f,0.f,0.f);
        #pragma unroll
        for (int kk = 0; kk < 9; kk++) {
            float4 wv = wq4[jb + kk];
            float4 dw = ((const float4*)dw_lds)[kk*64 + c4];
            float sx = (float)v[kk][0][0]*wv.x + (float)v[kk][1][0]*wv.y + (float)v[kk][2][0]*wv.z + (float)v[kk][3][0]*wv.w;
            float sy = (float)v[kk][0][1]*wv.x + (float)v[kk][1][1]*wv.y + (float)v[kk][2][1]*wv.z + (float)v[kk][3][1]*wv.w;
            float sz = (float)v[kk][0][2]*wv.x + (float)v[kk][1][2]*wv.y + (float)v[kk][2][2]*wv.z + (float)v[kk][3][2]*wv.w;
            float sw = (float)v[kk][0][3]*wv.x + (float)v[kk][1][3]*wv.y + (float)v[kk][2][3]*wv.z + (float)v[kk][3][3]*wv.w;
            acc.x += sx * dw.x;
            acc.y += sy * dw.y;
            acc.z += sz * dw.z;
            acc.w += sw * dw.w;
        }
        half4_t o4;
        o4[0] = (_Float16)(acc.x + bv.x);
        o4[1] = (_Float16)(acc.y + bv.y);
        o4[2] = (_Float16)(acc.z + bv.z);
        o4[3] = (_Float16)(acc.w + bv.w);
        ((half4_t*)out)[(size_t)p*64 + c4] = o4;
    }
}

// ---------------- xg = x*a + img; LayerNorm over C (f16 x,a; fp32 img; f16 out) ----------------
__global__ void __launch_bounds__(256) gate_ln_kernel(const _Float16* __restrict__ x, const _Float16* __restrict__ a,
        const float* __restrict__ img, const float* __restrict__ g, const float* __restrict__ bb,
        _Float16* __restrict__ out) {
    int t = threadIdx.x;
    int lane = t & 63;
    int wv = t >> 6;
    int p = blockIdx.x*4 + wv;
    half4_t xh = ((const half4_t*)x)[p*64 + lane];
    half4_t ah = ((const half4_t*)a)[p*64 + lane];
    float4 iv = ((const float4*)img)[p*64 + lane];
    float4 v;
    v.x = (float)xh[0]*(float)ah[0] + iv.x;
    v.y = (float)xh[1]*(float)ah[1] + iv.y;
    v.z = (float)xh[2]*(float)ah[2] + iv.z;
    v.w = (float)xh[3]*(float)ah[3] + iv.w;
    float s = v.x + v.y + v.z + v.w;
    float s2 = v.x*v.x + v.y*v.y + v.z*v.z + v.w*v.w;
    #pragma unroll
    for (int o = 1; o < 64; o <<= 1) { s += __shfl_xor(s, o); s2 += __shfl_xor(s2, o); }
    float m = s * (1.f/256.f);
    float var = s2 * (1.f/256.f) - m*m;
    float r = rsqrtf(var + 1e-5f);
    float4 gv = ((const float4*)g)[lane];
    float4 bv = ((const float4*)bb)[lane];
    half4_t o4;
    o4[0] = (_Float16)((v.x - m)*r*gv.x + bv.x);
    o4[1] = (_Float16)((v.y - m)*r*gv.y + bv.y);
    o4[2] = (_Float16)((v.z - m)*r*gv.z + bv.z);
    o4[3] = (_Float16)((v.w - m)*r*gv.w + bv.w);
    ((half4_t*)out)[p*64 + lane] = o4;
}

// ---------------- depthwise 3x3 pad=1 + gelu (NHWC, f16 in/out) ----------------
__global__ void __launch_bounds__(256) dw3x3_kernel(const _Float16* __restrict__ in, const float* __restrict__ wt,
        const float* __restrict__ bias, _Float16* __restrict__ out) {
    // XCD-aware swizzle: grid 16384 -> each XCD covers 2 consecutive batches
    int raw = blockIdx.x;
    int swz = (raw & 7) * 2048 + (raw >> 3);
    int gid = swz*256 + threadIdx.x;
    int c4 = gid & 63;
    int p = gid >> 6;
    int w = p & 63;
    int h = (p >> 6) & 63;
    int b = p >> 12;
    float4 acc = ((const float4*)bias)[c4];
    #pragma unroll
    for (int ki = 0; ki < 3; ki++) {
        int hh = h + ki - 1;
        if (hh < 0 || hh >= 64) continue;
        #pragma unroll
        for (int kj = 0; kj < 3; kj++) {
            int wwp = w + kj - 1;
            if (wwp < 0 || wwp >= 64) continue;
            half4_t v = ((const half4_t*)in)[((b*64 + hh)*64 + wwp)*64 + c4];
            float4 wv = ((const float4*)wt)[(ki*3 + kj)*64 + c4];
            acc.x += (float)v[0]*wv.x; acc.y += (float)v[1]*wv.y;
            acc.z += (float)v[2]*wv.z; acc.w += (float)v[3]*wv.w;
        }
    }
    half4_t o4;
    o4[0] = (_Float16)gelu_f(acc.x);
    o4[1] = (_Float16)gelu_f(acc.y);
    o4[2] = (_Float16)gelu_f(acc.z);
    o4[3] = (_Float16)gelu_f(acc.w);
    ((half4_t*)out)[p*64 + c4] = o4;
}

// ---------------- 8-token cross attention via MFMA + alpha residual ----------------
// Per block: 64 pixels. scores = MFMA(dense_tile, t) -> softmax (8-lane groups)
// -> weights to LDS f16 -> out = MFMA(w, t^T) + dense*alpha.
__global__ void __launch_bounds__(256) attn_mfma_kernel(const _Float16* __restrict__ dense,
        const float* __restrict__ tok, const float* __restrict__ alpha, _Float16* __restrict__ out) {
    __shared__ __align__(16) _Float16 d_lds[64*264];   // [px][c] pad
    __shared__ __align__(16) _Float16 t_q[16*264];     // [q][c], rows 8..15 zero
    __shared__ __align__(16) _Float16 t_t[258*24];     // [c][q] padded rows, zero-filled
    __shared__ __align__(16) _Float16 w_lds[64*40];    // [px][k], k>=8 zero
    __shared__ float al_s[256];
    int t = threadIdx.x;
    int wid = t >> 6, lane = t & 63;
    int quad = lane >> 4, l16 = lane & 15;
    int p0 = blockIdx.x * 64;
    int b = p0 >> 12;

    // zero-fill pass (avoid NaN-poisoned unused lanes in MFMA)
    for (int i = t; i < 16*264; i += 256) t_q[i] = (_Float16)0.f;
    for (int i = t; i < 258*24; i += 256) t_t[i] = (_Float16)0.f;
    for (int i = t; i < 64*40;  i += 256) w_lds[i] = (_Float16)0.f;
    __syncthreads();

    // stage dense tile
    const half8_t* dh = (const half8_t*)dense + (size_t)p0*32;
    for (int i = t; i < 2048; i += 256) {
        int r = i >> 5, c8 = i & 31;
        *(half8_t*)&d_lds[r*264 + c8*8] = dh[i];
    }
    // stage tokens (fp32 -> f16, both layouts)
    for (int i = t; i < 512; i += 256) {
        int q = i >> 6, j = i & 63;
        float4 tv = ((const float4*)tok)[(b*8 + q)*64 + j];
        int c0 = j*4;
        t_q[q*264 + c0 + 0] = (_Float16)tv.x;
        t_q[q*264 + c0 + 1] = (_Float16)tv.y;
        t_q[q*264 + c0 + 2] = (_Float16)tv.z;
        t_q[q*264 + c0 + 3] = (_Float16)tv.w;
        t_t[(c0 + 0)*24 + q] = (_Float16)tv.x;
        t_t[(c0 + 1)*24 + q] = (_Float16)tv.y;
        t_t[(c0 + 2)*24 + q] = (_Float16)tv.z;
        t_t[(c0 + 3)*24 + q] = (_Float16)tv.w;
    }
    al_s[t] = alpha[t];
    __syncthreads();

    // GEMM1: scores[px][q], px rows wid*16..+15
    floatx4 s4;
    s4[0]=0.f; s4[1]=0.f; s4[2]=0.f; s4[3]=0.f;
    #pragma unroll
    for (int ks = 0; ks < 8; ks++) {
        int k = ks*32 + quad*8;
        half8_t a = *(const half8_t*)&d_lds[(wid*16 + l16)*264 + k];
        half8_t bf = *(const half8_t*)&t_q[l16*264 + k];
        s4 = __builtin_amdgcn_mfma_f32_16x16x32_f16(a, bf, s4, 0, 0, 0);
    }
    // softmax over q (8-lane groups within l16; lanes l16>=8 compute harmless zeros)
    float wgt[4];
    #pragma unroll
    for (int r = 0; r < 4; r++) {
        float sc = s4[r] * 0.0625f;
        float mx = sc;
        mx = fmaxf(mx, __shfl_xor(mx, 1));
        mx = fmaxf(mx, __shfl_xor(mx, 2));
        mx = fmaxf(mx, __shfl_xor(mx, 4));
        float e = expf(sc - mx);
        float dn = e;
        dn += __shfl_xor(dn, 1);
        dn += __shfl_xor(dn, 2);
        dn += __shfl_xor(dn, 4);
        wgt[r] = e / dn;
    }
    if (l16 < 8) {
        #pragma unroll
        for (int r = 0; r < 4; r++)
            w_lds[(wid*16 + quad*4 + r)*40 + l16] = (_Float16)wgt[r];
    }
    __syncthreads();

    // GEMM2: out[px][c] = w x t + dense*alpha
    half8_t aw = *(const half8_t*)&w_lds[(wid*16 + l16)*40 + quad*8];
    floatx4 z4; z4[0]=0.f; z4[1]=0.f; z4[2]=0.f; z4[3]=0.f;
    floatx4 acc[16];
    #pragma unroll
    for (int nf = 0; nf < 16; nf++) {
        half8_t bf = *(const half8_t*)&t_t[(nf*16 + l16)*24 + quad*8];
        acc[nf] = __builtin_amdgcn_mfma_f32_16x16x32_f16(aw, bf, z4, 0, 0, 0);
    }
    #pragma unroll
    for (int nf = 0; nf < 16; nf++) {
        int co = nf*16 + l16;
        float al = al_s[co];
        #pragma unroll
        for (int r = 0; r < 4; r++) {
            int px = wid*16 + quad*4 + r;
            float d = (float)d_lds[px*264 + co];
            float o = acc[nf][r] + d*al;
            out[(size_t)(p0 + px)*256 + co] = (_Float16)o;
        }
    }
}

extern "C" void kernel_launch(void* const* d_in, const int* in_sizes, int n_in,
                              void* d_out, int out_size, void* d_ws, size_t ws_size,
                              hipStream_t stream) {
    const float* image_embed = (const float*)d_in[0];
    const float* inter_p     = (const float*)d_in[1];
    const float* intra_p     = (const float*)d_in[2];
    const float* masks       = (const float*)d_in[3];
    const float* proj_w      = (const float*)d_in[4];
    const float* proj_b      = (const float*)d_in[5];
    const float* lin_w       = (const float*)d_in[6];
    const float* lin_b       = (const float*)d_in[7];
    const float* tok_g       = (const float*)d_in[8];
    const float* tok_b       = (const float*)d_in[9];
    const float* alpha       = (const float*)d_in[10];
    const float* in_w        = (const float*)d_in[11];
    const float* in_b        = (const float*)d_in[12];
    const float* off0_w      = (const float*)d_in[13];
    const float* off0_b      = (const float*)d_in[14];
    const float* dw0_w       = (const float*)d_in[15];
    const float* dw0_b       = (const float*)d_in[16];
    const float* off1_w      = (const float*)d_in[17];
    const float* off1_b      = (const float*)d_in[18];
    const float* dw1_w       = (const float*)d_in[19];
    const float* dw1_b       = (const float*)d_in[20];
    const float* cv_w        = (const float*)d_in[21];
    const float* cv_b        = (const float*)d_in[22];
    const float* ln_g        = (const float*)d_in[23];
    const float* ln_b        = (const float*)d_in[24];
    const float* op0_w       = (const float*)d_in[25];
    const float* op0_b       = (const float*)d_in[26];
    const float* op1_w       = (const float*)d_in[27];
    const float* op1_b       = (const float*)d_in[28];
    const float* op2_w       = (const float*)d_in[29];
    const float* op2_b       = (const float*)d_in[30];
    const float* out0_w      = (const float*)d_in[31];
    const float* out0_b      = (const float*)d_in[32];
    const float* out1_w      = (const float*)d_in[33];
    const float* out1_b      = (const float*)d_in[34];
    (void)ws_size; (void)in_sizes; (void)n_in; (void)out_size;

    float* ws = (float*)d_ws;
    const size_t BIG = (size_t)PP * CC;     // 16,777,216 floats (64 MiB)
    float* A   = ws;                        // img fp32 -> (Y0H|Y1H f16)
    float* Bb  = A + BIG;                   // XH|A1H f16 -> ATH f16
    float* Cb  = Bb + BIG;                  // A2H|AH f16 -> DENH|O0H f16
    float* OFF = Cb + BIG;                  // [P][27]
    float* TOK = OFF + (size_t)PP*27;       // [16][8][256]
    float* DWT0 = TOK + BB*QQ*CC;
    float* DWT1 = DWT0 + 9*256;
    float* OP1T = DWT1 + 9*256;
    _Float16* WH_IN   = (_Float16*)(OP1T + 9*256);
    _Float16* WH_CV   = WH_IN + 65536;
    _Float16* WH_OP0  = WH_CV + 65536;
    _Float16* WH_OP2  = WH_OP0 + 65536;
    _Float16* WH_OUT0 = WH_OP2 + 65536;
    _Float16* WH_OUT1 = WH_OUT0 + 32768;
    _Float16* WHOFF0  = WH_OUT1 + 32768;
    _Float16* WHOFF1  = WHOFF0 + 9*32*256;
    // f16 tensor aliases (each 32 MiB = PP*CC halves)
    _Float16* XH   = (_Float16*)Bb;              // x f16
    _Float16* A1H  = XH + (size_t)PP*CC;         // deform1 out
    _Float16* A2H  = (_Float16*)Cb;              // deform2 out
    _Float16* AH   = A2H + (size_t)PP*CC;        // a = cv out
    _Float16* XLNH = (_Float16*)d_out;           // LN out (d_out lower half; dead before final)
    _Float16* Y0H  = (_Float16*)A;               // op0 out (img dead after gate_ln)
    _Float16* Y1H  = Y0H + (size_t)PP*CC;        // dw3x3 out
    _Float16* DENH = (_Float16*)Cb;              // dense (A2H dead)
    _Float16* ATH  = (_Float16*)Bb;              // attn out (XH dead)
    _Float16* O0H  = (_Float16*)Cb + (size_t)PP*CC;  // out0 out, 16 MiB (AH dead)

    prep_weights_kernel<<<(9*32*256 + 255)/256, 256, 0, stream>>>(
        off0_w, off1_w, dw0_w, dw1_w, op1_w,
        in_w, cv_w, op0_w, op2_w, out0_w, out1_w,
        DWT0, DWT1, OP1T,
        WH_IN, WH_CV, WH_OP0, WH_OP2, WH_OUT0, WH_OUT1, WHOFF0, WHOFF1);
    token_kernel<<<BB*QQ, 256, 0, stream>>>(inter_p, intra_p, proj_w, proj_b,
                                            lin_w, lin_b, tok_g, tok_b, TOK);
    // img = ie*(1+pe) -> NHWC fp32
    img_pe_kernel<<<dim3(HWs/32, CC/32, BB), dim3(32,8), 0, stream>>>(image_embed, intra_p, masks, A);
    // x = gelu(conv1x1(img)) -> f16 only
    conv1x1_mfma<256,256,1,0,false,1><<<PP/64, 256, 0, stream>>>(A, WH_IN, in_b, nullptr, nullptr, XH);
    // deform block 1 (dil=1)
    off_conv_mfma<1><<<BB*HH, 256, 0, stream>>>(XH, WHOFF0, off0_b, OFF);
    deform_kernel<1><<<BB*HH*2, 256, 0, stream>>>(XH, OFF, DWT0, dw0_b, A1H);
    // deform block 2 (dil=3)
    off_conv_mfma<3><<<BB*HH, 256, 0, stream>>>(A1H, WHOFF1, off1_b, OFF);
    deform_kernel<3><<<BB*HH*2, 256, 0, stream>>>(A1H, OFF, DWT1, dw1_b, A2H);
    // a = conv1x1(a2) -> f16
    conv1x1_mfma<256,256,0,0,true,1><<<PP/64, 256, 0, stream>>>(A2H, WH_CV, cv_b, nullptr, nullptr, AH);
    // x_ln = LN2d(x*a + img) -> f16
    gate_ln_kernel<<<PP/4, 256, 0, stream>>>(XH, AH, A, ln_g, ln_b, XLNH);
    // y0 = conv1x1(x_ln) -> f16
    conv1x1_mfma<256,256,0,0,true,1><<<PP/64, 256, 0, stream>>>(XLNH, WH_OP0, op0_b, nullptr, nullptr, Y0H);
    // y1 = gelu(dw3x3(y0)) -> f16
    dw3x3_kernel<<<PP*64/256, 256, 0, stream>>>(Y0H, OP1T, op1_b, Y1H);
    // dense = conv1x1(y1) + x_ln -> f16
    conv1x1_mfma<256,256,0,2,true,1><<<PP/64, 256, 0, stream>>>(Y1H, WH_OP2, op2_b, XLNH, nullptr, DENH);
    // attn = softmax-xattn(dense, t) + dense*alpha -> f16 (MFMA version)
    attn_mfma_kernel<<<PP/64, 256, 0, stream>>>(DENH, TOK, alpha, ATH);
    // o0 = gelu(conv1x1_128(attn)) -> f16
    conv1x1_mfma<256,128,1,0,true,1><<<PP/64, 256, 0, stream>>>(ATH, WH_OUT0, out0_b, nullptr, nullptr, O0H);
    // o = conv1x1(o0) -> NCHW fp32 directly into d_out (fused transpose)
    conv1x1_mfma<128,256,0,0,true,3><<<PP/64, 256, 0, stream>>>(O0H, WH_OUT1, out1_b, nullptr, (float*)d_out, nullptr);
}

// Round 4
// 769.910 us; speedup vs baseline: 1.6524x; 1.0566x over previous
//
#include <hip/hip_runtime.h>
#include <math.h>

#define BB 16
#define CC 256
#define HH 64
#define WW 64
#define HWs 4096
#define PP 65536   // BB*HWs
#define QQ 8
#define NN 9

typedef _Float16 half8_t __attribute__((ext_vector_type(8)));
typedef _Float16 half4_t __attribute__((ext_vector_type(4)));
typedef _Float16 half2_t __attribute__((ext_vector_type(2)));
typedef float floatx4 __attribute__((ext_vector_type(4)));

__device__ __forceinline__ float gelu_f(float x) {
    return 0.5f * x * (1.0f + erff(x * 0.70710678118654752f));
}

// ---------------- weight prep ----------------
__global__ void prep_weights_kernel(const float* __restrict__ off0_w, const float* __restrict__ off1_w,
                                    const float* __restrict__ dw0_w, const float* __restrict__ dw1_w,
                                    const float* __restrict__ op1_w,
                                    const float* __restrict__ in_w, const float* __restrict__ cv_w,
                                    const float* __restrict__ op0_w, const float* __restrict__ op2_w,
                                    const float* __restrict__ out0_w, const float* __restrict__ out1_w,
                                    float* __restrict__ dwt0, float* __restrict__ dwt1,
                                    float* __restrict__ op1t,
                                    _Float16* __restrict__ wh_in, _Float16* __restrict__ wh_cv,
                                    _Float16* __restrict__ wh_op0, _Float16* __restrict__ wh_op2,
                                    _Float16* __restrict__ wh_out0, _Float16* __restrict__ wh_out1,
                                    _Float16* __restrict__ whoff0, _Float16* __restrict__ whoff1) {
    int i = blockIdx.x * 256 + threadIdx.x;
    if (i < 9*256) {
        int c = i & 255;
        int tap = i >> 8;
        dwt0[i] = dw0_w[c*9 + tap];
        dwt1[i] = dw1_w[c*9 + tap];
        op1t[i] = op1_w[c*9 + tap];
    }
    if (i < 65536) {            // [256][256] f16 direct casts
        wh_in[i]  = (_Float16)in_w[i];
        wh_cv[i]  = (_Float16)cv_w[i];
        wh_op0[i] = (_Float16)op0_w[i];
        wh_op2[i] = (_Float16)op2_w[i];
    }
    if (i < 32768) {            // out0: [128][256], out1: [256][128]
        wh_out0[i] = (_Float16)out0_w[i];
        wh_out1[i] = (_Float16)out1_w[i];
    }
    if (i < 9*32*256) {         // whoff[tap][k32][ci], zero-padded k>=27
        int ci = i & 255;
        int k32 = (i >> 8) & 31;
        int tap = i >> 13;
        float v0 = 0.f, v1 = 0.f;
        if (k32 < 27) {
            v0 = off0_w[(k32*256 + ci)*9 + tap];
            v1 = off1_w[(k32*256 + ci)*9 + tap];
        }
        whoff0[i] = (_Float16)v0;
        whoff1[i] = (_Float16)v1;
    }
}

// ---------------- token path ----------------
__global__ void token_kernel(const float* __restrict__ inter, const float* __restrict__ intra,
                             const float* __restrict__ proj_w, const float* __restrict__ proj_b,
                             const float* __restrict__ lin_w, const float* __restrict__ lin_b,
                             const float* __restrict__ tok_g, const float* __restrict__ tok_b,
                             float* __restrict__ t_out) {
    int bq = blockIdx.x;
    int b = bq >> 3, q = bq & 7;
    int c = threadIdx.x;
    __shared__ float inter_s[256];
    __shared__ float pt_s[9];
    __shared__ float g_s[256];
    __shared__ float red[256];
    __shared__ float stat[2];
    inter_s[c] = inter[(b*QQ + q)*CC + c];
    __syncthreads();
    for (int n = 0; n < 9; n++) {
        red[c] = inter_s[c] * intra[(b*NN + n)*CC + c];
        __syncthreads();
        for (int s = 128; s > 0; s >>= 1) {
            if (c < s) red[c] += red[c + s];
            __syncthreads();
        }
        if (c == 0) pt_s[n] = red[0];
        __syncthreads();
    }
    float u = proj_b[c];
    for (int k = 0; k < 256; k++) u += inter_s[k] * proj_w[k*CC + c];
    for (int n = 0; n < 9; n++) u += pt_s[n] * proj_w[(256 + n)*CC + c];
    g_s[c] = gelu_f(u);
    __syncthreads();
    float v = lin_b[c];
    for (int k = 0; k < 256; k++) v += g_s[k] * lin_w[k*CC + c];
    red[c] = v;
    __syncthreads();
    for (int s = 128; s > 0; s >>= 1) { if (c < s) red[c] += red[c + s]; __syncthreads(); }
    if (c == 0) stat[0] = red[0] * (1.0f/256.0f);
    __syncthreads();
    float m = stat[0];
    red[c] = (v - m)*(v - m);
    __syncthreads();
    for (int s = 128; s > 0; s >>= 1) { if (c < s) red[c] += red[c + s]; __syncthreads(); }
    if (c == 0) stat[1] = red[0] * (1.0f/256.0f);
    __syncthreads();
    float var = stat[1];
    float r = rsqrtf(var + 1e-5f);
    t_out[(b*QQ + q)*CC + c] = (v - m) * r * tok_g[c] + tok_b[c];
}

// ---------------- img = ie*(1+pe), NCHW -> NHWC transpose, f16 out ----------------
__global__ void img_pe_kernel(const float* __restrict__ ie, const float* __restrict__ intra,
                              const float* __restrict__ masks, _Float16* __restrict__ img) {
    int b = blockIdx.z;
    int c0 = blockIdx.y * 32;
    int s0 = blockIdx.x * 32;
    __shared__ float tile[32][33];
    __shared__ float intra_s[9][32];
    __shared__ float mask_s[9][32];
    int tx = threadIdx.x, ty = threadIdx.y;
    int t = ty*32 + tx;
    for (int i = t; i < 288; i += 256) {
        int n = i >> 5, j = i & 31;
        intra_s[n][j] = intra[(b*NN + n)*CC + c0 + j];
        mask_s[n][j]  = masks[(b*NN + n)*HWs + s0 + j];
    }
    __syncthreads();
    #pragma unroll
    for (int r = 0; r < 4; r++) {
        int cl = ty + 8*r;
        float val = ie[(b*CC + c0 + cl)*HWs + s0 + tx];
        float pe = 0.f;
        #pragma unroll
        for (int n = 0; n < 9; n++) pe += intra_s[n][cl] * mask_s[n][tx];
        tile[cl][tx] = val * (1.0f + pe);
    }
    __syncthreads();
    #pragma unroll
    for (int r = 0; r < 4; r++) {
        int sl = ty + 8*r;
        img[(b*HWs + s0 + sl)*CC + c0 + tx] = (_Float16)tile[tx][sl];
    }
}

// ---------------- MFMA 1x1 conv (GEMM), f16 in ----------------
// RES: 0 none, 2 f16 residual (perm layout)
// OUT: 1 = f16 out with permuted-B packed stores (thread holds NF consecutive co)
//      3 = fp32 NCHW direct (standard B mapping, float4-over-r stores)
template<int CI, int CO, int ACT, int RES, int OUT>
__global__ void __launch_bounds__(256) conv1x1_mfma(const _Float16* __restrict__ in, const _Float16* __restrict__ Wh,
        const float* __restrict__ bias, const _Float16* __restrict__ res, float* __restrict__ out,
        _Float16* __restrict__ outh) {
    constexpr int KS = CI/32;        // k-steps
    constexpr int NF = CO/64;        // n-frags per wave
    constexpr int LDR = CI + 8;      // halves per LDS row (+16B pad)
    __shared__ __align__(16) _Float16 a_lds[64*LDR];
    int t = threadIdx.x;
    int wid = t >> 6, lane = t & 63;
    int quad = lane >> 4, l16 = lane & 15;
    int p0 = blockIdx.x * 64;
    {
        const half8_t* inh = (const half8_t*)in + (size_t)p0*(CI/8);
        for (int i = t; i < 64*(CI/8); i += 256) {
            int r = i/(CI/8), c8 = i%(CI/8);
            *(half8_t*)&a_lds[r*LDR + c8*8] = inh[i];
        }
    }
    __syncthreads();
    int n0 = wid*(CO/4);
    floatx4 acc[4][NF];
    #pragma unroll
    for (int mf = 0; mf < 4; mf++)
        #pragma unroll
        for (int nf = 0; nf < NF; nf++)
            #pragma unroll
            for (int r = 0; r < 4; r++) acc[mf][nf][r] = 0.f;
    for (int ks = 0; ks < KS; ks++) {
        int k = ks*32 + quad*8;
        half8_t a[4];
        #pragma unroll
        for (int mf = 0; mf < 4; mf++)
            a[mf] = *(const half8_t*)&a_lds[(mf*16 + l16)*LDR + k];
        half8_t bfr[NF];
        #pragma unroll
        for (int nf = 0; nf < NF; nf++) {
            // OUT==1: permuted rows so each thread ends with NF consecutive co
            int brow = (OUT == 1) ? (n0 + l16*NF + nf) : (n0 + nf*16 + l16);
            bfr[nf] = *(const half8_t*)&Wh[(size_t)brow*CI + k];
        }
        #pragma unroll
        for (int mf = 0; mf < 4; mf++)
            #pragma unroll
            for (int nf = 0; nf < NF; nf++)
                acc[mf][nf] = __builtin_amdgcn_mfma_f32_16x16x32_f16(a[mf], bfr[nf], acc[mf][nf], 0, 0, 0);
    }
    if (OUT == 1) {
        int cb = n0 + l16*NF;
        float bs[NF];
        #pragma unroll
        for (int j = 0; j < NF; j++) bs[j] = bias[cb + j];
        #pragma unroll
        for (int mf = 0; mf < 4; mf++) {
            #pragma unroll
            for (int r = 0; r < 4; r++) {
                int p = p0 + mf*16 + quad*4 + r;
                half4_t rh;
                if (RES == 2 && NF == 4) rh = *(const half4_t*)&res[(size_t)p*CO + cb];
                _Float16 tmp[NF];
                #pragma unroll
                for (int j = 0; j < NF; j++) {
                    float v = acc[mf][j][r] + bs[j];
                    if (ACT) v = gelu_f(v);
                    if (RES == 2 && NF == 4) v += (float)rh[j];
                    tmp[j] = (_Float16)v;
                }
                if (NF == 4) {
                    half4_t o4; o4[0]=tmp[0]; o4[1]=tmp[1]; o4[2]=tmp[2]; o4[3]=tmp[3];
                    *(half4_t*)&outh[(size_t)p*CO + cb] = o4;
                } else {
                    half2_t o2; o2[0]=tmp[0]; o2[1]=tmp[1];
                    *(half2_t*)&outh[(size_t)p*CO + cb] = o2;
                }
            }
        }
    } else {  // OUT == 3: fp32 NCHW direct
        size_t bb = (size_t)(p0 >> 12) * ((size_t)CO * HWs) + (size_t)(p0 & 4095);
        #pragma unroll
        for (int nf = 0; nf < NF; nf++) {
            int co = n0 + nf*16 + l16;
            float bs = bias[co];
            #pragma unroll
            for (int mf = 0; mf < 4; mf++) {
                float4 vst;
                vst.x = acc[mf][nf][0] + bs;
                vst.y = acc[mf][nf][1] + bs;
                vst.z = acc[mf][nf][2] + bs;
                vst.w = acc[mf][nf][3] + bs;
                if (ACT) { vst.x=gelu_f(vst.x); vst.y=gelu_f(vst.y); vst.z=gelu_f(vst.z); vst.w=gelu_f(vst.w); }
                *(float4*)&out[bb + (size_t)co*HWs + mf*16 + quad*4] = vst;
            }
        }
    }
}

// ---------------- cv conv (256->256) fused with gate + LayerNorm over C ----------------
// a = conv(in); v = x*a + img; out = LN_C(v)*g + b   (all f16 tensors, fp32 math)
__global__ void __launch_bounds__(256) conv_cv_ln_kernel(const _Float16* __restrict__ in, const _Float16* __restrict__ Wh,
        const float* __restrict__ bias, const _Float16* __restrict__ X, const _Float16* __restrict__ IMG,
        const float* __restrict__ g, const float* __restrict__ bb2, _Float16* __restrict__ out) {
    constexpr int CI = 256, KS = 8, NF = 4, LDR = 264;
    __shared__ __align__(16) _Float16 a_lds[64*LDR];
    __shared__ float rs[64][4];
    __shared__ float rs2[64][4];
    __shared__ float st[64][2];
    int t = threadIdx.x;
    int wid = t >> 6, lane = t & 63;
    int quad = lane >> 4, l16 = lane & 15;
    int p0 = blockIdx.x * 64;
    {
        const half8_t* inh = (const half8_t*)in + (size_t)p0*32;
        for (int i = t; i < 2048; i += 256) {
            int r = i >> 5, c8 = i & 31;
            *(half8_t*)&a_lds[r*LDR + c8*8] = inh[i];
        }
    }
    __syncthreads();
    int n0 = wid*64;
    floatx4 acc[4][4];
    #pragma unroll
    for (int mf = 0; mf < 4; mf++)
        #pragma unroll
        for (int nf = 0; nf < 4; nf++)
            #pragma unroll
            for (int r = 0; r < 4; r++) acc[mf][nf][r] = 0.f;
    for (int ks = 0; ks < KS; ks++) {
        int k = ks*32 + quad*8;
        half8_t a[4];
        #pragma unroll
        for (int mf = 0; mf < 4; mf++)
            a[mf] = *(const half8_t*)&a_lds[(mf*16 + l16)*LDR + k];
        half8_t bfr[4];
        #pragma unroll
        for (int nf = 0; nf < 4; nf++)
            bfr[nf] = *(const half8_t*)&Wh[(size_t)(n0 + l16*4 + nf)*CI + k];
        #pragma unroll
        for (int mf = 0; mf < 4; mf++)
            #pragma unroll
            for (int nf = 0; nf < 4; nf++)
                acc[mf][nf] = __builtin_amdgcn_mfma_f32_16x16x32_f16(a[mf], bfr[nf], acc[mf][nf], 0, 0, 0);
    }
    int cb = n0 + l16*4;
    float bs[4];
    #pragma unroll
    for (int j = 0; j < 4; j++) bs[j] = bias[cb + j];
    // v = x*a + img; per-pixel partial sums across 16-lane groups
    #pragma unroll
    for (int mf = 0; mf < 4; mf++) {
        #pragma unroll
        for (int r = 0; r < 4; r++) {
            int px_l = mf*16 + quad*4 + r;
            size_t off = (size_t)(p0 + px_l)*256 + cb;
            half4_t xh = *(const half4_t*)&X[off];
            half4_t ih = *(const half4_t*)&IMG[off];
            float s = 0.f, s2 = 0.f;
            #pragma unroll
            for (int j = 0; j < 4; j++) {
                float v = acc[mf][j][r] + bs[j];
                v = (float)xh[j]*v + (float)ih[j];
                acc[mf][j][r] = v;
                s += v; s2 += v*v;
            }
            s += __shfl_xor(s, 1); s2 += __shfl_xor(s2, 1);
            s += __shfl_xor(s, 2); s2 += __shfl_xor(s2, 2);
            s += __shfl_xor(s, 4); s2 += __shfl_xor(s2, 4);
            s += __shfl_xor(s, 8); s2 += __shfl_xor(s2, 8);
            if (l16 == 0) { rs[px_l][wid] = s; rs2[px_l][wid] = s2; }
        }
    }
    __syncthreads();
    if (t < 64) {
        float m = 0.f, q = 0.f;
        #pragma unroll
        for (int w = 0; w < 4; w++) { m += rs[t][w]; q += rs2[t][w]; }
        m *= (1.0f/256.0f);
        float var = q*(1.0f/256.0f) - m*m;
        st[t][0] = m;
        st[t][1] = rsqrtf(var + 1e-5f);
    }
    __syncthreads();
    float ga[4], ba[4];
    #pragma unroll
    for (int j = 0; j < 4; j++) { ga[j] = g[cb + j]; ba[j] = bb2[cb + j]; }
    #pragma unroll
    for (int mf = 0; mf < 4; mf++) {
        #pragma unroll
        for (int r = 0; r < 4; r++) {
            int px_l = mf*16 + quad*4 + r;
            float m = st[px_l][0];
            float ri = st[px_l][1];
            half4_t o4;
            #pragma unroll
            for (int j = 0; j < 4; j++)
                o4[j] = (_Float16)((acc[mf][j][r] - m)*ri*ga[j] + ba[j]);
            *(half4_t*)&out[(size_t)(p0 + px_l)*256 + cb] = o4;
        }
    }
}

// ---------------- MFMA 3x3 offset conv (f16 input) -> [p][27] ----------------
template<int DIL>
__global__ void __launch_bounds__(256) off_conv_mfma(const _Float16* __restrict__ x, const _Float16* __restrict__ Wh,
        const float* __restrict__ bias, float* __restrict__ off) {
    constexpr int LDR = 264;    // 256 + 16B pad, halves
    __shared__ __align__(16) _Float16 xs[70*LDR];   // w = -3..66 at idx w+3
    int raw = blockIdx.x;
    int bh = (raw & 7) * 128 + (raw >> 3);
    int b = bh >> 6, h = bh & 63;
    int t = threadIdx.x;
    int wid = t >> 6, lane = t & 63;
    int quad = lane >> 4, l16 = lane & 15;
    for (int i = t; i < 6*LDR; i += 256) {
        int r = i/LDR, c = i%LDR;
        int row = (r < 3) ? r : (64 + r);   // 0,1,2, 67,68,69
        xs[row*LDR + c] = (_Float16)0.f;
    }
    floatx4 acc[2];
    #pragma unroll
    for (int nf = 0; nf < 2; nf++)
        #pragma unroll
        for (int r = 0; r < 4; r++) acc[nf][r] = 0.f;
    for (int ki = 0; ki < 3; ki++) {
        int hrow = h + (ki - 1)*DIL;
        __syncthreads();
        if (hrow >= 0 && hrow < 64) {
            const half8_t* row = (const half8_t*)(x + ((size_t)(b*64 + hrow)*64) * 256);
            for (int i = t; i < 2048; i += 256) {
                int r = i >> 5, c8 = i & 31;
                *(half8_t*)&xs[(r + 3)*LDR + c8*8] = row[r*32 + c8];
            }
        } else {
            half8_t z = (half8_t)((_Float16)0.f);
            for (int i = t; i < 2048; i += 256) {
                int r = i >> 5, c8 = i & 31;
                *(half8_t*)&xs[(r + 3)*LDR + c8*8] = z;
            }
        }
        __syncthreads();
        #pragma unroll
        for (int kj = 0; kj < 3; kj++) {
            const _Float16* wt = Wh + (size_t)(ki*3 + kj)*32*256;
            int wrow = wid*16 + l16 + (kj - 1)*DIL + 3;
            #pragma unroll
            for (int cs = 0; cs < 8; cs++) {
                int k = cs*32 + quad*8;
                half8_t a = *(const half8_t*)&xs[wrow*LDR + k];
                half8_t b0 = *(const half8_t*)&wt[(size_t)l16*256 + k];
                half8_t b1 = *(const half8_t*)&wt[(size_t)(16 + l16)*256 + k];
                acc[0] = __builtin_amdgcn_mfma_f32_16x16x32_f16(a, b0, acc[0], 0, 0, 0);
                acc[1] = __builtin_amdgcn_mfma_f32_16x16x32_f16(a, b1, acc[1], 0, 0, 0);
            }
        }
    }
    int pbase = (b*64 + h)*64;
    #pragma unroll
    for (int nf = 0; nf < 2; nf++) {
        int kcol = nf*16 + l16;
        if (kcol < 27) {
            float bs = bias[kcol];
            #pragma unroll
            for (int r = 0; r < 4; r++) {
                int w = wid*16 + quad*4 + r;
                off[(size_t)(pbase + w)*27 + kcol] = acc[nf][r] + bs;
            }
        }
    }
}

// ---------------- modulated deformable depthwise 3x3 (f16 src/out, fp32 math) ----------------
// stage A precomputes per-(w,tap) uniform bilinear weights + byte offsets in LDS.
// Inner loop: issue ALL 36 corner loads, then sched_barrier(0) pins them (no sinking),
// so consumption starts at vmcnt(32) instead of serializing at vmcnt(0) per tap.
template<int DIL>
__global__ void __launch_bounds__(256) deform_kernel(const _Float16* __restrict__ src, const float* __restrict__ off,
        const float* __restrict__ dwt, const float* __restrict__ dwb, _Float16* __restrict__ out) {
    int raw = blockIdx.x;                       // 0..2047
    int swz = (raw & 7) * 256 + (raw >> 3);     // XCD k -> 2 consecutive batches
    int whalf = swz & 1;
    int bh = swz >> 1;
    int b = bh >> 6, h = bh & 63;
    int t = threadIdx.x;
    int c4 = t & 63;
    int ps = t >> 6;

    __shared__ float4 wq4[288];
    __shared__ int4   iq4[288];
    __shared__ float  dw_lds[9*256];

    for (int i = t; i < 9*256; i += 256) dw_lds[i] = dwt[i];

    for (int j = t; j < 288; j += 256) {
        int lw = j / 9;
        int kk = j - lw*9;
        int w = whalf*32 + lw;
        int p = (b*64 + h)*64 + w;
        const float* op = off + (size_t)p*27;
        float ox = op[kk];
        float oy = op[9 + kk];
        float mm = op[18 + kk];
        mm = 1.0f / (1.0f + expf(-mm));
        int ki = kk / 3, kj = kk - ki*3;
        float py = (float)(h - DIL + ki*DIL) + oy;
        float px = (float)(w - DIL + kj*DIL) + ox;
        float y0f = floorf(py), x0f = floorf(px);
        float wy = py - y0f, wx = px - x0f;
        int y0 = (int)y0f, x0 = (int)x0f;
        int y1 = y0 + 1, x1 = x0 + 1;
        float w00 = (1.f - wy)*(1.f - wx)*mm;
        float w01 = (1.f - wy)*wx*mm;
        float w10 = wy*(1.f - wx)*mm;
        float w11 = wy*wx*mm;
        bool yv0 = (y0 >= 0) && (y0 < 64);
        bool yv1 = (y1 >= 0) && (y1 < 64);
        bool xv0 = (x0 >= 0) && (x0 < 64);
        bool xv1 = (x1 >= 0) && (x1 < 64);
        int y0c = min(max(y0, 0), 63), y1c = min(max(y1, 0), 63);
        int x0c = min(max(x0, 0), 63), x1c = min(max(x1, 0), 63);
        int base = b*4096;
        float4 wv;
        wv.x = (yv0 && xv0) ? w00 : 0.f;
        wv.y = (yv0 && xv1) ? w01 : 0.f;
        wv.z = (yv1 && xv0) ? w10 : 0.f;
        wv.w = (yv1 && xv1) ? w11 : 0.f;
        wq4[j] = wv;
        int4 iv;
        iv.x = (base + y0c*64 + x0c) << 9;   // *512 B per pixel (256 ch * 2B)
        iv.y = (base + y0c*64 + x1c) << 9;
        iv.z = (base + y1c*64 + x0c) << 9;
        iv.w = (base + y1c*64 + x1c) << 9;
        iq4[j] = iv;
    }
    __syncthreads();

    float4 bv = ((const float4*)dwb)[c4];
    const char* srcb = (const char*)src + (size_t)c4*8;
    for (int i = 0; i < 8; i++) {
        int lw = ps*8 + i;
        int jb = lw*9;
        int w = whalf*32 + lw;
        int p = (b*64 + h)*64 + w;
        // phase A: issue all 36 corner loads (pinned below)
        half4_t v[9][4];
        #pragma unroll
        for (int kk = 0; kk < 9; kk++) {
            int4 iv = iq4[jb + kk];
            int o0 = __builtin_amdgcn_readfirstlane(iv.x);
            int o1 = __builtin_amdgcn_readfirstlane(iv.y);
            int o2 = __builtin_amdgcn_readfirstlane(iv.z);
            int o3 = __builtin_amdgcn_readfirstlane(iv.w);
            v[kk][0] = *(const half4_t*)(srcb + o0);
            v[kk][1] = *(const half4_t*)(srcb + o1);
            v[kk][2] = *(const half4_t*)(srcb + o2);
            v[kk][3] = *(const half4_t*)(srcb + o3);
        }
        __builtin_amdgcn_sched_barrier(0);   // do NOT sink loads past this point
        // phase B: accumulate
        float4 acc = make_float4(0.f,0.f,0.f,0.f);
        #pragma unroll
        for (int kk = 0; kk < 9; kk++) {
            float4 wv = wq4[jb + kk];
            float4 dw = ((const float4*)dw_lds)[kk*64 + c4];
            float sx = (float)v[kk][0][0]*wv.x + (float)v[kk][1][0]*wv.y + (float)v[kk][2][0]*wv.z + (float)v[kk][3][0]*wv.w;
            float sy = (float)v[kk][0][1]*wv.x + (float)v[kk][1][1]*wv.y + (float)v[kk][2][1]*wv.z + (float)v[kk][3][1]*wv.w;
            float sz = (float)v[kk][0][2]*wv.x + (float)v[kk][1][2]*wv.y + (float)v[kk][2][2]*wv.z + (float)v[kk][3][2]*wv.w;
            float sw = (float)v[kk][0][3]*wv.x + (float)v[kk][1][3]*wv.y + (float)v[kk][2][3]*wv.z + (float)v[kk][3][3]*wv.w;
            acc.x += sx * dw.x;
            acc.y += sy * dw.y;
            acc.z += sz * dw.z;
            acc.w += sw * dw.w;
        }
        half4_t o4;
        o4[0] = (_Float16)(acc.x + bv.x);
        o4[1] = (_Float16)(acc.y + bv.y);
        o4[2] = (_Float16)(acc.z + bv.z);
        o4[3] = (_Float16)(acc.w + bv.w);
        ((half4_t*)out)[(size_t)p*64 + c4] = o4;
    }
}

// ---------------- depthwise 3x3 pad=1 + gelu (NHWC, f16 in/out) ----------------
__global__ void __launch_bounds__(256) dw3x3_kernel(const _Float16* __restrict__ in, const float* __restrict__ wt,
        const float* __restrict__ bias, _Float16* __restrict__ out) {
    int raw = blockIdx.x;
    int swz = (raw & 7) * 2048 + (raw >> 3);
    int gid = swz*256 + threadIdx.x;
    int c4 = gid & 63;
    int p = gid >> 6;
    int w = p & 63;
    int h = (p >> 6) & 63;
    int b = p >> 12;
    float4 acc = ((const float4*)bias)[c4];
    #pragma unroll
    for (int ki = 0; ki < 3; ki++) {
        int hh = h + ki - 1;
        if (hh < 0 || hh >= 64) continue;
        #pragma unroll
        for (int kj = 0; kj < 3; kj++) {
            int wwp = w + kj - 1;
            if (wwp < 0 || wwp >= 64) continue;
            half4_t v = ((const half4_t*)in)[((b*64 + hh)*64 + wwp)*64 + c4];
            float4 wv = ((const float4*)wt)[(ki*3 + kj)*64 + c4];
            acc.x += (float)v[0]*wv.x; acc.y += (float)v[1]*wv.y;
            acc.z += (float)v[2]*wv.z; acc.w += (float)v[3]*wv.w;
        }
    }
    half4_t o4;
    o4[0] = (_Float16)gelu_f(acc.x);
    o4[1] = (_Float16)gelu_f(acc.y);
    o4[2] = (_Float16)gelu_f(acc.z);
    o4[3] = (_Float16)gelu_f(acc.w);
    ((half4_t*)out)[p*64 + c4] = o4;
}

// ---------------- 8-token cross attention via MFMA + alpha residual ----------------
__global__ void __launch_bounds__(256) attn_mfma_kernel(const _Float16* __restrict__ dense,
        const float* __restrict__ tok, const float* __restrict__ alpha, _Float16* __restrict__ out) {
    __shared__ __align__(16) _Float16 d_lds[64*264];   // [px][c] pad
    __shared__ __align__(16) _Float16 t_q[16*264];     // [q][c], rows 8..15 zero
    __shared__ __align__(16) _Float16 t_t[258*24];     // [c][q] padded rows, zero-filled
    __shared__ __align__(16) _Float16 w_lds[64*40];    // [px][k], k>=8 zero
    __shared__ float al_s[256];
    int t = threadIdx.x;
    int wid = t >> 6, lane = t & 63;
    int quad = lane >> 4, l16 = lane & 15;
    int p0 = blockIdx.x * 64;
    int b = p0 >> 12;

    for (int i = t; i < 16*264; i += 256) t_q[i] = (_Float16)0.f;
    for (int i = t; i < 258*24; i += 256) t_t[i] = (_Float16)0.f;
    for (int i = t; i < 64*40;  i += 256) w_lds[i] = (_Float16)0.f;
    __syncthreads();

    const half8_t* dh = (const half8_t*)dense + (size_t)p0*32;
    for (int i = t; i < 2048; i += 256) {
        int r = i >> 5, c8 = i & 31;
        *(half8_t*)&d_lds[r*264 + c8*8] = dh[i];
    }
    for (int i = t; i < 512; i += 256) {
        int q = i >> 6, j = i & 63;
        float4 tv = ((const float4*)tok)[(b*8 + q)*64 + j];
        int c0 = j*4;
        t_q[q*264 + c0 + 0] = (_Float16)tv.x;
        t_q[q*264 + c0 + 1] = (_Float16)tv.y;
        t_q[q*264 + c0 + 2] = (_Float16)tv.z;
        t_q[q*264 + c0 + 3] = (_Float16)tv.w;
        t_t[(c0 + 0)*24 + q] = (_Float16)tv.x;
        t_t[(c0 + 1)*24 + q] = (_Float16)tv.y;
        t_t[(c0 + 2)*24 + q] = (_Float16)tv.z;
        t_t[(c0 + 3)*24 + q] = (_Float16)tv.w;
    }
    al_s[t] = alpha[t];
    __syncthreads();

    floatx4 s4;
    s4[0]=0.f; s4[1]=0.f; s4[2]=0.f; s4[3]=0.f;
    #pragma unroll
    for (int ks = 0; ks < 8; ks++) {
        int k = ks*32 + quad*8;
        half8_t a = *(const half8_t*)&d_lds[(wid*16 + l16)*264 + k];
        half8_t bf = *(const half8_t*)&t_q[l16*264 + k];
        s4 = __builtin_amdgcn_mfma_f32_16x16x32_f16(a, bf, s4, 0, 0, 0);
    }
    float wgt[4];
    #pragma unroll
    for (int r = 0; r < 4; r++) {
        float sc = s4[r] * 0.0625f;
        float mx = sc;
        mx = fmaxf(mx, __shfl_xor(mx, 1));
        mx = fmaxf(mx, __shfl_xor(mx, 2));
        mx = fmaxf(mx, __shfl_xor(mx, 4));
        float e = expf(sc - mx);
        float dn = e;
        dn += __shfl_xor(dn, 1);
        dn += __shfl_xor(dn, 2);
        dn += __shfl_xor(dn, 4);
        wgt[r] = e / dn;
    }
    if (l16 < 8) {
        #pragma unroll
        for (int r = 0; r < 4; r++)
            w_lds[(wid*16 + quad*4 + r)*40 + l16] = (_Float16)wgt[r];
    }
    __syncthreads();

    half8_t aw = *(const half8_t*)&w_lds[(wid*16 + l16)*40 + quad*8];
    floatx4 z4; z4[0]=0.f; z4[1]=0.f; z4[2]=0.f; z4[3]=0.f;
    floatx4 acc[16];
    #pragma unroll
    for (int nf = 0; nf < 16; nf++) {
        half8_t bf = *(const half8_t*)&t_t[(nf*16 + l16)*24 + quad*8];
        acc[nf] = __builtin_amdgcn_mfma_f32_16x16x32_f16(aw, bf, z4, 0, 0, 0);
    }
    #pragma unroll
    for (int nf = 0; nf < 16; nf++) {
        int co = nf*16 + l16;
        float al = al_s[co];
        #pragma unroll
        for (int r = 0; r < 4; r++) {
            int px = wid*16 + quad*4 + r;
            float d = (float)d_lds[px*264 + co];
            float o = acc[nf][r] + d*al;
            out[(size_t)(p0 + px)*256 + co] = (_Float16)o;
        }
    }
}

extern "C" void kernel_launch(void* const* d_in, const int* in_sizes, int n_in,
                              void* d_out, int out_size, void* d_ws, size_t ws_size,
                              hipStream_t stream) {
    const float* image_embed = (const float*)d_in[0];
    const float* inter_p     = (const float*)d_in[1];
    const float* intra_p     = (const float*)d_in[2];
    const float* masks       = (const float*)d_in[3];
    const float* proj_w      = (const float*)d_in[4];
    const float* proj_b      = (const float*)d_in[5];
    const float* lin_w       = (const float*)d_in[6];
    const float* lin_b       = (const float*)d_in[7];
    const float* tok_g       = (const float*)d_in[8];
    const float* tok_b       = (const float*)d_in[9];
    const float* alpha       = (const float*)d_in[10];
    const float* in_w        = (const float*)d_in[11];
    const float* in_b        = (const float*)d_in[12];
    const float* off0_w      = (const float*)d_in[13];
    const float* off0_b      = (const float*)d_in[14];
    const float* dw0_w       = (const float*)d_in[15];
    const float* dw0_b       = (const float*)d_in[16];
    const float* off1_w      = (const float*)d_in[17];
    const float* off1_b      = (const float*)d_in[18];
    const float* dw1_w       = (const float*)d_in[19];
    const float* dw1_b       = (const float*)d_in[20];
    const float* cv_w        = (const float*)d_in[21];
    const float* cv_b        = (const float*)d_in[22];
    const float* ln_g        = (const float*)d_in[23];
    const float* ln_b        = (const float*)d_in[24];
    const float* op0_w       = (const float*)d_in[25];
    const float* op0_b       = (const float*)d_in[26];
    const float* op1_w       = (const float*)d_in[27];
    const float* op1_b       = (const float*)d_in[28];
    const float* op2_w       = (const float*)d_in[29];
    const float* op2_b       = (const float*)d_in[30];
    const float* out0_w      = (const float*)d_in[31];
    const float* out0_b      = (const float*)d_in[32];
    const float* out1_w      = (const float*)d_in[33];
    const float* out1_b      = (const float*)d_in[34];
    (void)ws_size; (void)in_sizes; (void)n_in; (void)out_size;

    float* ws = (float*)d_ws;
    const size_t BIG = (size_t)PP * CC;     // 16,777,216 floats (64 MiB)
    float* A   = ws;
    float* Bb  = A + BIG;
    float* Cb  = Bb + BIG;
    float* OFF = Cb + BIG;                  // [P][27]
    float* TOK = OFF + (size_t)PP*27;       // [16][8][256]
    float* DWT0 = TOK + BB*QQ*CC;
    float* DWT1 = DWT0 + 9*256;
    float* OP1T = DWT1 + 9*256;
    _Float16* WH_IN   = (_Float16*)(OP1T + 9*256);
    _Float16* WH_CV   = WH_IN + 65536;
    _Float16* WH_OP0  = WH_CV + 65536;
    _Float16* WH_OP2  = WH_OP0 + 65536;
    _Float16* WH_OUT0 = WH_OP2 + 65536;
    _Float16* WH_OUT1 = WH_OUT0 + 32768;
    _Float16* WHOFF0  = WH_OUT1 + 32768;
    _Float16* WHOFF1  = WHOFF0 + 9*32*256;
    // f16 tensor aliases (each 32 MiB = PP*CC halves)
    _Float16* IMGH = (_Float16*)A;               // img f16 (dead after cv_ln)
    _Float16* Y0H  = (_Float16*)A;               // op0 out (reuses IMGH)
    _Float16* Y1H  = Y0H + (size_t)PP*CC;        // dw3x3 out
    _Float16* XH   = (_Float16*)Bb;              // x f16 (dead after cv_ln)
    _Float16* A1H  = XH + (size_t)PP*CC;         // deform1 out
    _Float16* ATH  = (_Float16*)Bb;              // attn out (reuses XH)
    _Float16* A2H  = (_Float16*)Cb;              // deform2 out (dead after cv_ln)
    _Float16* DENH = (_Float16*)Cb;              // dense (reuses A2H)
    _Float16* O0H  = (_Float16*)Cb + (size_t)PP*CC;  // out0 out (16 MiB used)
    _Float16* XLNH = (_Float16*)d_out;           // LN out (d_out; dead before final write)

    prep_weights_kernel<<<(9*32*256 + 255)/256, 256, 0, stream>>>(
        off0_w, off1_w, dw0_w, dw1_w, op1_w,
        in_w, cv_w, op0_w, op2_w, out0_w, out1_w,
        DWT0, DWT1, OP1T,
        WH_IN, WH_CV, WH_OP0, WH_OP2, WH_OUT0, WH_OUT1, WHOFF0, WHOFF1);
    token_kernel<<<BB*QQ, 256, 0, stream>>>(inter_p, intra_p, proj_w, proj_b,
                                            lin_w, lin_b, tok_g, tok_b, TOK);
    // img = ie*(1+pe) -> NHWC f16
    img_pe_kernel<<<dim3(HWs/32, CC/32, BB), dim3(32,8), 0, stream>>>(image_embed, intra_p, masks, IMGH);
    // x = gelu(conv1x1(img)) -> f16 (perm stores)
    conv1x1_mfma<256,256,1,0,1><<<PP/64, 256, 0, stream>>>(IMGH, WH_IN, in_b, nullptr, nullptr, XH);
    // deform block 1 (dil=1)
    off_conv_mfma<1><<<BB*HH, 256, 0, stream>>>(XH, WHOFF0, off0_b, OFF);
    deform_kernel<1><<<BB*HH*2, 256, 0, stream>>>(XH, OFF, DWT0, dw0_b, A1H);
    // deform block 2 (dil=3)
    off_conv_mfma<3><<<BB*HH, 256, 0, stream>>>(A1H, WHOFF1, off1_b, OFF);
    deform_kernel<3><<<BB*HH*2, 256, 0, stream>>>(A1H, OFF, DWT1, dw1_b, A2H);
    // x_ln = LN2d(x*conv(a2) + img) -> f16 (fused cv conv + gate + LN)
    conv_cv_ln_kernel<<<PP/64, 256, 0, stream>>>(A2H, WH_CV, cv_b, XH, IMGH, ln_g, ln_b, XLNH);
    // y0 = conv1x1(x_ln) -> f16
    conv1x1_mfma<256,256,0,0,1><<<PP/64, 256, 0, stream>>>(XLNH, WH_OP0, op0_b, nullptr, nullptr, Y0H);
    // y1 = gelu(dw3x3(y0)) -> f16
    dw3x3_kernel<<<PP*64/256, 256, 0, stream>>>(Y0H, OP1T, op1_b, Y1H);
    // dense = conv1x1(y1) + x_ln -> f16
    conv1x1_mfma<256,256,0,2,1><<<PP/64, 256, 0, stream>>>(Y1H, WH_OP2, op2_b, XLNH, nullptr, DENH);
    // attn = softmax-xattn(dense, t) + dense*alpha -> f16
    attn_mfma_kernel<<<PP/64, 256, 0, stream>>>(DENH, TOK, alpha, ATH);
    // o0 = gelu(conv1x1_128(attn)) -> f16
    conv1x1_mfma<256,128,1,0,1><<<PP/64, 256, 0, stream>>>(ATH, WH_OUT0, out0_b, nullptr, nullptr, O0H);
    // o = conv1x1(o0) -> NCHW fp32 directly into d_out (fused transpose)
    conv1x1_mfma<128,256,0,0,3><<<PP/64, 256, 0, stream>>>(O0H, WH_OUT1, out1_b, nullptr, (float*)d_out, nullptr);
}